// Round 11
// baseline (360.239 us; speedup 1.0000x reference)
//
#include <hip/hip_runtime.h>

#define BN_EPS 1e-5f
#define MAXBINS 128   // bins of 512 rows; requires N <= 65536 (col packs in 16 bits)

typedef __attribute__((ext_vector_type(8))) short bf16x8;
typedef __attribute__((ext_vector_type(4))) float f32x4;
typedef __attribute__((ext_vector_type(4))) int i32x4;
typedef __attribute__((ext_vector_type(2))) int i32x2;

__device__ __forceinline__ ushort f2bf(float f) {
  uint u = __float_as_uint(f);
  u += 0x7fffu + ((u >> 16) & 1u);
  return (ushort)(u >> 16);
}
__device__ __forceinline__ float bf2f(ushort u) {
  return __uint_as_float((uint)u << 16);
}
__device__ __forceinline__ uint pack2bf(float a, float b) {
  return (uint)f2bf(a) | ((uint)f2bf(b) << 16);
}
__device__ __forceinline__ uint ntu(const uint* p) {
  return __builtin_nontemporal_load(p);
}
__device__ __forceinline__ int nti(const int* p) {
  return __builtin_nontemporal_load(p);
}
__device__ __forceinline__ i32x4 nt4(const int* p) {
  return __builtin_nontemporal_load((const i32x4*)p);
}
// acc[0..7] += v * bf16x8(wv)
__device__ __forceinline__ void fma8(float acc[8], uint4 wv, float v) {
  acc[0] += v * __uint_as_float(wv.x << 16);
  acc[1] += v * __uint_as_float(wv.x & 0xffff0000u);
  acc[2] += v * __uint_as_float(wv.y << 16);
  acc[3] += v * __uint_as_float(wv.y & 0xffff0000u);
  acc[4] += v * __uint_as_float(wv.z << 16);
  acc[5] += v * __uint_as_float(wv.z & 0xffff0000u);
  acc[6] += v * __uint_as_float(wv.w << 16);
  acc[7] += v * __uint_as_float(wv.w & 0xffff0000u);
}

// ---------------------------------------------------------------------------
// One-time weight transpose to bf16 (L2-resident broadcast tables).
// ---------------------------------------------------------------------------
__global__ __launch_bounds__(256) void prep_weights(
    const float* __restrict__ We, const float* __restrict__ Wf,
    ushort* __restrict__ Wet, ushort* __restrict__ Wtg) {
  int i = blockIdx.x * 256 + threadIdx.x;
  if (i < 32768) {
    int col = i >> 9, k = i & 511;
    Wet[(size_t)col * 512 + k] = f2bf(We[(size_t)k * 64 + col]);
  } else if (i < 32768 + 24576) {
    int j = i - 32768;
    int col = j / 192, k = j % 192;
    float v = 0.f;
    if (col < 40)       v = Wf[(size_t)k * 40 + col];
    else if (col < 80)  { if (k >= 64) v = Wf[(size_t)(128 + k) * 40 + (col - 40)]; }
    else if (col < 120) { if (k >= 64) v = Wf[(size_t)(256 + k) * 40 + (col - 80)]; }
    Wtg[(size_t)col * 192 + k] = f2bf(v);
  }
}

// ---------------------------------------------------------------------------
// Embed via MFMA, no LDS: hb = bf16( relu(x @ We + b) )  [N,512]@[512,64]
// ---------------------------------------------------------------------------
__global__ __launch_bounds__(256) void embed_mfma(
    const float* __restrict__ x, const ushort* __restrict__ Wet,
    const float* __restrict__ b, ushort* __restrict__ hb, int N) {
  const int tid  = threadIdx.x;
  const int wv   = tid >> 6;
  const int lane = tid & 63;
  const int m16  = lane & 15;
  const int kg   = lane >> 4;
  const int row0 = blockIdx.x * 128 + wv * 32;

  f32x4 acc[2][4];
#pragma unroll
  for (int i = 0; i < 2; ++i)
#pragma unroll
    for (int t = 0; t < 4; ++t) acc[i][t] = (f32x4){0.f, 0.f, 0.f, 0.f};

#pragma unroll 4
  for (int ks = 0; ks < 16; ++ks) {
    const int kk = ks * 32 + kg * 8;
    bf16x8 afr[2];
#pragma unroll
    for (int i = 0; i < 2; ++i) {
      int grow = row0 + i * 16 + m16;
      grow = (grow < N) ? grow : (N - 1);
      const float* ap = x + (size_t)grow * 512 + kk;
      float4 lo = *reinterpret_cast<const float4*>(ap);
      float4 hi = *reinterpret_cast<const float4*>(ap + 4);
      uint4 pk;
      pk.x = pack2bf(lo.x, lo.y); pk.y = pack2bf(lo.z, lo.w);
      pk.z = pack2bf(hi.x, hi.y); pk.w = pack2bf(hi.z, hi.w);
      afr[i] = *reinterpret_cast<const bf16x8*>(&pk);
    }
#pragma unroll
    for (int t = 0; t < 4; ++t) {
      bf16x8 bfr = *reinterpret_cast<const bf16x8*>(
          Wet + (size_t)(t * 16 + m16) * 512 + kk);
      acc[0][t] = __builtin_amdgcn_mfma_f32_16x16x32_bf16(afr[0], bfr, acc[0][t], 0, 0, 0);
      acc[1][t] = __builtin_amdgcn_mfma_f32_16x16x32_bf16(afr[1], bfr, acc[1][t], 0, 0, 0);
    }
  }

#pragma unroll
  for (int i = 0; i < 2; ++i) {
    const int rbase = row0 + i * 16 + kg * 4;
#pragma unroll
    for (int t = 0; t < 4; ++t) {
      const int col = t * 16 + m16;
      const float bias = b[col];
#pragma unroll
      for (int reg = 0; reg < 4; ++reg) {
        int gr = rbase + reg;
        if (gr < N)
          hb[(size_t)gr * 64 + col] = f2bf(fmaxf(acc[i][t][reg] + bias, 0.f));
      }
    }
  }
}

// ---------------------------------------------------------------------------
// CSR build, two-level binned (bin = row>>9). Both graphs per launch.
// ---------------------------------------------------------------------------
__global__ __launch_bounds__(256) void bin_hist2(
    const int* __restrict__ r1, int E1c, int* __restrict__ gbin1,
    const int* __restrict__ r2, int E2c, int* __restrict__ gbin2, int nbins) {
  __shared__ int lb[MAXBINS];
  const int tid = threadIdx.x;
  const bool g  = blockIdx.x >= 256;
  const int* rows = g ? r2 : r1;
  const int  E    = g ? E2c : E1c;
  int* gbin       = g ? gbin2 : gbin1;
  const int bid   = blockIdx.x & 255;
  if (tid < nbins) lb[tid] = 0;
  __syncthreads();
  for (int i = bid * 256 + tid; i < E; i += 256 * 256)
    atomicAdd(&lb[nti(rows + i) >> 9], 1);
  __syncthreads();
  if (tid < nbins && lb[tid]) atomicAdd(&gbin[tid], lb[tid]);
}

__device__ __forceinline__ void scan_bins_dev(
    const int* gbin, int* gbase, int* gcur, int nbins, int lane) {
  int carry = 0;
  for (int ch = 0; ch * 64 < nbins; ++ch) {
    int idx = ch * 64 + lane;
    int v = (idx < nbins) ? gbin[idx] : 0;
    int inc = v;
#pragma unroll
    for (int off = 1; off < 64; off <<= 1) {
      int y = __shfl_up(inc, off);
      if (lane >= off) inc += y;
    }
    int ex = carry + inc - v;
    if (idx < nbins) { gbase[idx] = ex; gcur[idx] = ex; }
    carry += __shfl(inc, 63);
  }
}

__global__ __launch_bounds__(64) void bin_scan(
    const int* __restrict__ gbin1, int* __restrict__ gbase1, int* __restrict__ gcur1,
    const int* __restrict__ gbin2, int* __restrict__ gbase2, int* __restrict__ gcur2,
    int nbins) {
  int lane = threadIdx.x;
  scan_bins_dev(gbin1, gbase1, gcur1, nbins, lane);
  scan_bins_dev(gbin2, gbase2, gcur2, nbins, lane);
}

// Staging record: int2( col | (row&511)<<16 , val_bits_f32 ). Both graphs.
__global__ __launch_bounds__(256) void bin_scatter2(
    const int* __restrict__ r1, const int* __restrict__ c1,
    const float* __restrict__ v1, int E1c, int* __restrict__ gcur1,
    int2* __restrict__ S1,
    const int* __restrict__ r2, const int* __restrict__ c2,
    const float* __restrict__ v2, int E2c, int* __restrict__ gcur2,
    int2* __restrict__ S2, int nbins) {
  __shared__ int lcnt[MAXBINS];
  __shared__ int lcur[MAXBINS];
  const int tid = threadIdx.x;
  const bool g  = blockIdx.x >= 256;
  const int* rows = g ? r2 : r1;
  const int* cols = g ? c2 : c1;
  const float* vals = g ? v2 : v1;
  const int  E    = g ? E2c : E1c;
  int* gcur       = g ? gcur2 : gcur1;
  int2* S         = g ? S2 : S1;
  const int bid   = blockIdx.x & 255;

  for (int e0 = bid * 2048; e0 < E; e0 += 256 * 2048) {
    int i0 = e0 + tid * 8;
    int r[8], c[8], vb[8];
    if (i0 + 8 <= E) {
      i32x4 a = nt4(rows + i0);
      i32x4 b = nt4(rows + i0 + 4);
      r[0]=a.x; r[1]=a.y; r[2]=a.z; r[3]=a.w; r[4]=b.x; r[5]=b.y; r[6]=b.z; r[7]=b.w;
      a = nt4(cols + i0);
      b = nt4(cols + i0 + 4);
      c[0]=a.x; c[1]=a.y; c[2]=a.z; c[3]=a.w; c[4]=b.x; c[5]=b.y; c[6]=b.z; c[7]=b.w;
      a = nt4((const int*)vals + i0);
      b = nt4((const int*)vals + i0 + 4);
      vb[0]=a.x; vb[1]=a.y; vb[2]=a.z; vb[3]=a.w; vb[4]=b.x; vb[5]=b.y; vb[6]=b.z; vb[7]=b.w;
    } else {
#pragma unroll
      for (int t = 0; t < 8; ++t) {
        int i = i0 + t;
        bool ok = i < E;
        r[t]  = ok ? rows[i] : -1;
        c[t]  = ok ? cols[i] : 0;
        vb[t] = ok ? __float_as_int(vals[i]) : 0;
      }
    }
    if (tid < nbins) lcnt[tid] = 0;
    __syncthreads();
#pragma unroll
    for (int t = 0; t < 8; ++t)
      if (r[t] >= 0) atomicAdd(&lcnt[r[t] >> 9], 1);
    __syncthreads();
    if (tid < nbins) {
      int n = lcnt[tid];
      lcur[tid] = n ? atomicAdd(&gcur[tid], n) : 0;
    }
    __syncthreads();
#pragma unroll
    for (int t = 0; t < 8; ++t) {
      if (r[t] >= 0) {
        int pos = atomicAdd(&lcur[r[t] >> 9], 1);
        i32x2 rec = {c[t] | ((r[t] & 511) << 16), vb[t]};
        __builtin_nontemporal_store(rec, (i32x2*)&S[pos]);
      }
    }
    __syncthreads();
  }
}

// One block per (graph, bin). Final edge record: uint( col | bf16(val)<<16 ).
__global__ __launch_bounds__(256) void csr_finalize(
    const int2* __restrict__ S1, const int* __restrict__ gbase1,
    int* __restrict__ rp1, uint* __restrict__ Eo1, int Etot1,
    const int2* __restrict__ S2, const int* __restrict__ gbase2,
    int* __restrict__ rp2, uint* __restrict__ Eo2, int Etot2,
    int N, int nbins) {
  __shared__ int cnt[512];
  __shared__ int cur[512];
  const int tid = threadIdx.x;
  const int b = blockIdx.x % nbins;
  const int g = blockIdx.x / nbins;
  const int2* S     = g ? S2 : S1;
  const int* gbase  = g ? gbase2 : gbase1;
  int* rp           = g ? rp2 : rp1;
  uint* Eo          = g ? Eo2 : Eo1;
  const int Etot    = g ? Etot2 : Etot1;

  const int base = gbase[b];
  const int end  = (b + 1 < nbins) ? gbase[b + 1] : Etot;
  const int r0   = b << 9;
  const int nrows = min(512, N - r0);

  for (int l = tid; l < 512; l += 256) cnt[l] = 0;
  __syncthreads();
  for (int j = base + tid; j < end; j += 256)
    atomicAdd(&cnt[S[j].x >> 16], 1);
  __syncthreads();
  if (tid < 64) {
    int carry = 0;
#pragma unroll
    for (int ch = 0; ch < 8; ++ch) {
      int v = cnt[ch * 64 + tid];
      int inc = v;
#pragma unroll
      for (int off = 1; off < 64; off <<= 1) {
        int y = __shfl_up(inc, off);
        if (tid >= off) inc += y;
      }
      inc += carry;
      cnt[ch * 64 + tid] = inc;
      carry = __shfl(inc, 63);
    }
  }
  __syncthreads();
  for (int l = tid; l < 512; l += 256)
    cur[l] = base + ((l > 0) ? cnt[l - 1] : 0);
  for (int l = tid; l < nrows; l += 256)
    rp[r0 + l + 1] = base + cnt[l];
  if (b == 0 && tid == 0) rp[0] = 0;
  __syncthreads();
  for (int j = base + tid; j < end; j += 256) {
    int2 m = S[j];
    int pos = atomicAdd(&cur[m.x >> 16], 1);
    Eo[pos] = (uint)(m.x & 0xffff) | ((uint)f2bf(__int_as_float(m.y)) << 16);
  }
}

// ---------------------------------------------------------------------------
// Conv1 gather + fused BN. One wave per row (grid-stride), 32-edge chunks,
// MLP=4. Meta loads are non-temporal (protect hb table in L2).
// ---------------------------------------------------------------------------
__global__ __launch_bounds__(256) void conv1_gather(
    const ushort* __restrict__ hb,
    const int* __restrict__ rp1, const uint* __restrict__ E1,
    const int* __restrict__ rp2, const uint* __restrict__ E2,
    const float* __restrict__ gamma, const float* __restrict__ beta,
    const float* __restrict__ mean, const float* __restrict__ var,
    ushort* __restrict__ h1b, int N, int nwaves) {
  const int wid  = (blockIdx.x * blockDim.x + threadIdx.x) >> 6;
  const int lane = threadIdx.x & 63;
  const int sub  = lane >> 3;
  const int q    = lane & 7;

  float sc1[8], sh1[8], sc2[8], sh2[8];
#pragma unroll
  for (int t4 = 0; t4 < 2; ++t4) {
    int f1 = q * 8 + t4 * 4;
    float4 gm = *reinterpret_cast<const float4*>(gamma + f1);
    float4 vr = *reinterpret_cast<const float4*>(var + f1);
    float4 mn = *reinterpret_cast<const float4*>(mean + f1);
    float4 bt = *reinterpret_cast<const float4*>(beta + f1);
    float s0 = gm.x * rsqrtf(vr.x + BN_EPS), s1 = gm.y * rsqrtf(vr.y + BN_EPS);
    float s2 = gm.z * rsqrtf(vr.z + BN_EPS), s3 = gm.w * rsqrtf(vr.w + BN_EPS);
    sc1[t4 * 4 + 0] = s0; sh1[t4 * 4 + 0] = bt.x - mn.x * s0;
    sc1[t4 * 4 + 1] = s1; sh1[t4 * 4 + 1] = bt.y - mn.y * s1;
    sc1[t4 * 4 + 2] = s2; sh1[t4 * 4 + 2] = bt.z - mn.z * s2;
    sc1[t4 * 4 + 3] = s3; sh1[t4 * 4 + 3] = bt.w - mn.w * s3;
    int f2 = 64 + f1;
    gm = *reinterpret_cast<const float4*>(gamma + f2);
    vr = *reinterpret_cast<const float4*>(var + f2);
    mn = *reinterpret_cast<const float4*>(mean + f2);
    bt = *reinterpret_cast<const float4*>(beta + f2);
    s0 = gm.x * rsqrtf(vr.x + BN_EPS); s1 = gm.y * rsqrtf(vr.y + BN_EPS);
    s2 = gm.z * rsqrtf(vr.z + BN_EPS); s3 = gm.w * rsqrtf(vr.w + BN_EPS);
    sc2[t4 * 4 + 0] = s0; sh2[t4 * 4 + 0] = bt.x - mn.x * s0;
    sc2[t4 * 4 + 1] = s1; sh2[t4 * 4 + 1] = bt.y - mn.y * s1;
    sc2[t4 * 4 + 2] = s2; sh2[t4 * 4 + 2] = bt.z - mn.z * s2;
    sc2[t4 * 4 + 3] = s3; sh2[t4 * 4 + 3] = bt.w - mn.w * s3;
  }

  for (int r = wid; r < N; r += nwaves) {
    float acc1[8] = {0, 0, 0, 0, 0, 0, 0, 0};
    float acc2[8] = {0, 0, 0, 0, 0, 0, 0, 0};
    {
      int s = rp1[r], e = rp1[r + 1];
      for (int j0 = s; j0 < e; j0 += 32) {
        int j = j0 + sub;
        uint m0 = (j      < e) ? ntu(E1 + j)      : 0u;
        uint m1 = (j + 8  < e) ? ntu(E1 + j + 8)  : 0u;
        uint m2 = (j + 16 < e) ? ntu(E1 + j + 16) : 0u;
        uint m3 = (j + 24 < e) ? ntu(E1 + j + 24) : 0u;
        uint4 w0 = *reinterpret_cast<const uint4*>(hb + (size_t)(m0 & 0xffffu) * 64 + q * 8);
        uint4 w1 = *reinterpret_cast<const uint4*>(hb + (size_t)(m1 & 0xffffu) * 64 + q * 8);
        uint4 w2 = *reinterpret_cast<const uint4*>(hb + (size_t)(m2 & 0xffffu) * 64 + q * 8);
        uint4 w3 = *reinterpret_cast<const uint4*>(hb + (size_t)(m3 & 0xffffu) * 64 + q * 8);
        fma8(acc1, w0, bf2f((ushort)(m0 >> 16)));
        fma8(acc1, w1, bf2f((ushort)(m1 >> 16)));
        fma8(acc1, w2, bf2f((ushort)(m2 >> 16)));
        fma8(acc1, w3, bf2f((ushort)(m3 >> 16)));
      }
    }
    {
      int s = rp2[r], e = rp2[r + 1];
      for (int j0 = s; j0 < e; j0 += 32) {
        int j = j0 + sub;
        uint m0 = (j      < e) ? ntu(E2 + j)      : 0u;
        uint m1 = (j + 8  < e) ? ntu(E2 + j + 8)  : 0u;
        uint m2 = (j + 16 < e) ? ntu(E2 + j + 16) : 0u;
        uint m3 = (j + 24 < e) ? ntu(E2 + j + 24) : 0u;
        uint4 w0 = *reinterpret_cast<const uint4*>(hb + (size_t)(m0 & 0xffffu) * 64 + q * 8);
        uint4 w1 = *reinterpret_cast<const uint4*>(hb + (size_t)(m1 & 0xffffu) * 64 + q * 8);
        uint4 w2 = *reinterpret_cast<const uint4*>(hb + (size_t)(m2 & 0xffffu) * 64 + q * 8);
        uint4 w3 = *reinterpret_cast<const uint4*>(hb + (size_t)(m3 & 0xffffu) * 64 + q * 8);
        fma8(acc2, w0, bf2f((ushort)(m0 >> 16)));
        fma8(acc2, w1, bf2f((ushort)(m1 >> 16)));
        fma8(acc2, w2, bf2f((ushort)(m2 >> 16)));
        fma8(acc2, w3, bf2f((ushort)(m3 >> 16)));
      }
    }
#pragma unroll
    for (int mask = 8; mask <= 32; mask <<= 1) {
#pragma unroll
      for (int t = 0; t < 8; ++t) {
        acc1[t] += __shfl_xor(acc1[t], mask);
        acc2[t] += __shfl_xor(acc2[t], mask);
      }
    }
    if (lane < 8) {
      uint4 p1, p2;
      p1.x = pack2bf(acc1[0] * sc1[0] + sh1[0], acc1[1] * sc1[1] + sh1[1]);
      p1.y = pack2bf(acc1[2] * sc1[2] + sh1[2], acc1[3] * sc1[3] + sh1[3]);
      p1.z = pack2bf(acc1[4] * sc1[4] + sh1[4], acc1[5] * sc1[5] + sh1[5]);
      p1.w = pack2bf(acc1[6] * sc1[6] + sh1[6], acc1[7] * sc1[7] + sh1[7]);
      p2.x = pack2bf(acc2[0] * sc2[0] + sh2[0], acc2[1] * sc2[1] + sh2[1]);
      p2.y = pack2bf(acc2[2] * sc2[2] + sh2[2], acc2[3] * sc2[3] + sh2[3]);
      p2.z = pack2bf(acc2[4] * sc2[4] + sh2[4], acc2[5] * sc2[5] + sh2[5]);
      p2.w = pack2bf(acc2[6] * sc2[6] + sh2[6], acc2[7] * sc2[7] + sh2[7]);
      ushort* dst = h1b + (size_t)r * 128 + q * 8;
      *reinterpret_cast<uint4*>(dst)      = p1;
      *reinterpret_cast<uint4*>(dst + 64) = p2;
    }
  }
}

// ---------------------------------------------------------------------------
// MFMA dense tail, no LDS: A = [hb | h1b] (N x 192 bf16), B from Wtg (L2).
//   cols 0:40 -> out (f32,+bias); 40:80 -> g1b; 80:120 -> g2b (bf16)
// ---------------------------------------------------------------------------
__global__ __launch_bounds__(256) void dense_tail_mfma(
    const ushort* __restrict__ hb, const ushort* __restrict__ h1b,
    const ushort* __restrict__ Wtg, const float* __restrict__ bfin,
    float* __restrict__ out, ushort* __restrict__ g1b, ushort* __restrict__ g2b,
    int N) {
  const int tid  = threadIdx.x;
  const int wv   = tid >> 6;
  const int lane = tid & 63;
  const int m16  = lane & 15;
  const int kg   = lane >> 4;
  const int row0 = blockIdx.x * 128;

  f32x4 acc[2][8];
#pragma unroll
  for (int i = 0; i < 2; ++i)
#pragma unroll
    for (int t = 0; t < 8; ++t) acc[i][t] = (f32x4){0.f, 0.f, 0.f, 0.f};

#pragma unroll
  for (int ks = 0; ks < 6; ++ks) {
    const int kk = ks * 32 + kg * 8;
    bf16x8 afr[2];
#pragma unroll
    for (int i = 0; i < 2; ++i) {
      int grow = row0 + wv * 32 + i * 16 + m16;
      grow = (grow < N) ? grow : (N - 1);
      const ushort* ap = (kk < 64) ? hb + (size_t)grow * 64 + kk
                                   : h1b + (size_t)grow * 128 + (kk - 64);
      afr[i] = *reinterpret_cast<const bf16x8*>(ap);
    }
#pragma unroll
    for (int t = 0; t < 8; ++t) {
      bf16x8 bfr = *reinterpret_cast<const bf16x8*>(
          Wtg + (size_t)(t * 16 + m16) * 192 + kk);
      acc[0][t] = __builtin_amdgcn_mfma_f32_16x16x32_bf16(afr[0], bfr, acc[0][t], 0, 0, 0);
      acc[1][t] = __builtin_amdgcn_mfma_f32_16x16x32_bf16(afr[1], bfr, acc[1][t], 0, 0, 0);
    }
  }

#pragma unroll
  for (int i = 0; i < 2; ++i) {
    const int rbase = row0 + wv * 32 + i * 16 + kg * 4;
#pragma unroll
    for (int t = 0; t < 8; ++t) {
      const int col = t * 16 + m16;
      if (col >= 120) continue;
      const float bias = (col < 40) ? bfin[col] : 0.f;
#pragma unroll
      for (int reg = 0; reg < 4; ++reg) {
        int gr = rbase + reg;
        if (gr < N) {
          float v = acc[i][t][reg];
          if (col < 40)       out[(size_t)gr * 40 + col] = v + bias;
          else if (col < 80)  g1b[(size_t)gr * 40 + (col - 40)] = f2bf(v);
          else                g2b[(size_t)gr * 40 + (col - 80)] = f2bf(v);
        }
      }
    }
  }
}

// ---------------------------------------------------------------------------
// Final add: out[r,:] += sum_{adj1} v*g1b[c,:] + sum_{adj2} v*g2b[c,:]
// 32-edge chunks, MLP=4, 8-lane subgroups; nt meta loads.
// ---------------------------------------------------------------------------
__global__ __launch_bounds__(256) void final_add_kernel(
    const ushort* __restrict__ g1b, const ushort* __restrict__ g2b,
    const int* __restrict__ rp1, const uint* __restrict__ E1,
    const int* __restrict__ rp2, const uint* __restrict__ E2,
    float* __restrict__ out, int N, int nwaves) {
  const int wid  = (blockIdx.x * blockDim.x + threadIdx.x) >> 6;
  const int lane = threadIdx.x & 63;
  const int sub  = lane >> 3;
  const int q    = lane & 7;
  const int off  = (q < 5) ? q * 8 : 0;

  for (int r = wid; r < N; r += nwaves) {
    float a1[8] = {0, 0, 0, 0, 0, 0, 0, 0};
    float a2[8] = {0, 0, 0, 0, 0, 0, 0, 0};
    {
      int s = rp1[r], e = rp1[r + 1];
      for (int j0 = s; j0 < e; j0 += 32) {
        int j = j0 + sub;
        uint m0 = (j      < e) ? ntu(E1 + j)      : 0u;
        uint m1 = (j + 8  < e) ? ntu(E1 + j + 8)  : 0u;
        uint m2 = (j + 16 < e) ? ntu(E1 + j + 16) : 0u;
        uint m3 = (j + 24 < e) ? ntu(E1 + j + 24) : 0u;
        uint4 w0 = *reinterpret_cast<const uint4*>(g1b + (size_t)(m0 & 0xffffu) * 40 + off);
        uint4 w1 = *reinterpret_cast<const uint4*>(g1b + (size_t)(m1 & 0xffffu) * 40 + off);
        uint4 w2 = *reinterpret_cast<const uint4*>(g1b + (size_t)(m2 & 0xffffu) * 40 + off);
        uint4 w3 = *reinterpret_cast<const uint4*>(g1b + (size_t)(m3 & 0xffffu) * 40 + off);
        fma8(a1, w0, bf2f((ushort)(m0 >> 16)));
        fma8(a1, w1, bf2f((ushort)(m1 >> 16)));
        fma8(a1, w2, bf2f((ushort)(m2 >> 16)));
        fma8(a1, w3, bf2f((ushort)(m3 >> 16)));
      }
    }
    {
      int s = rp2[r], e = rp2[r + 1];
      for (int j0 = s; j0 < e; j0 += 32) {
        int j = j0 + sub;
        uint m0 = (j      < e) ? ntu(E2 + j)      : 0u;
        uint m1 = (j + 8  < e) ? ntu(E2 + j + 8)  : 0u;
        uint m2 = (j + 16 < e) ? ntu(E2 + j + 16) : 0u;
        uint m3 = (j + 24 < e) ? ntu(E2 + j + 24) : 0u;
        uint4 w0 = *reinterpret_cast<const uint4*>(g2b + (size_t)(m0 & 0xffffu) * 40 + off);
        uint4 w1 = *reinterpret_cast<const uint4*>(g2b + (size_t)(m1 & 0xffffu) * 40 + off);
        uint4 w2 = *reinterpret_cast<const uint4*>(g2b + (size_t)(m2 & 0xffffu) * 40 + off);
        uint4 w3 = *reinterpret_cast<const uint4*>(g2b + (size_t)(m3 & 0xffffu) * 40 + off);
        fma8(a2, w0, bf2f((ushort)(m0 >> 16)));
        fma8(a2, w1, bf2f((ushort)(m1 >> 16)));
        fma8(a2, w2, bf2f((ushort)(m2 >> 16)));
        fma8(a2, w3, bf2f((ushort)(m3 >> 16)));
      }
    }
#pragma unroll
    for (int mask = 8; mask <= 32; mask <<= 1) {
#pragma unroll
      for (int t = 0; t < 8; ++t) {
        a1[t] += __shfl_xor(a1[t], mask);
        a2[t] += __shfl_xor(a2[t], mask);
      }
    }
    if (lane < 5) {
      float* p = out + (size_t)r * 40 + lane * 8;
      float4 o0 = *reinterpret_cast<const float4*>(p);
      float4 o1 = *reinterpret_cast<const float4*>(p + 4);
      o0.x += a1[0] + a2[0]; o0.y += a1[1] + a2[1];
      o0.z += a1[2] + a2[2]; o0.w += a1[3] + a2[3];
      o1.x += a1[4] + a2[4]; o1.y += a1[5] + a2[5];
      o1.z += a1[6] + a2[6]; o1.w += a1[7] + a2[7];
      *reinterpret_cast<float4*>(p)     = o0;
      *reinterpret_cast<float4*>(p + 4) = o1;
    }
  }
}

// ---------------------------------------------------------------------------
extern "C" void kernel_launch(void* const* d_in, const int* in_sizes, int n_in,
                              void* d_out, int out_size, void* d_ws, size_t ws_size,
                              hipStream_t stream) {
  const float* x     = (const float*)d_in[0];
  const int*   a1r   = (const int*)d_in[1];
  const int*   a1c   = (const int*)d_in[2];
  const float* a1v   = (const float*)d_in[3];
  const int*   a2r   = (const int*)d_in[4];
  const int*   a2c   = (const int*)d_in[5];
  const float* a2v   = (const float*)d_in[6];
  const float* We    = (const float*)d_in[7];
  const float* be    = (const float*)d_in[8];
  const float* gamma = (const float*)d_in[9];
  const float* beta  = (const float*)d_in[10];
  const float* mean  = (const float*)d_in[11];
  const float* var   = (const float*)d_in[12];
  const float* Wf    = (const float*)d_in[13];
  const float* bf    = (const float*)d_in[14];
  float* out = (float*)d_out;

  const int N  = in_sizes[0] / 512;
  const int E1 = in_sizes[1];
  const int E2 = in_sizes[4];
  const int nbins = (N + 511) >> 9;   // requires N <= 65536

  char* p = (char*)d_ws;
  auto alloc = [&](size_t bytes) {
    char* q = p; p += (bytes + 255) & ~(size_t)255; return q;
  };
  ushort* hb   = (ushort*)alloc((size_t)N * 64 * 2);
  ushort* h1b  = (ushort*)alloc((size_t)N * 128 * 2);
  ushort* g1b  = (ushort*)alloc((size_t)N * 40 * 2);
  ushort* g2b  = (ushort*)alloc((size_t)N * 40 * 2);
  ushort* Wet  = (ushort*)alloc((size_t)64 * 512 * 2);
  ushort* Wtg  = (ushort*)alloc((size_t)128 * 192 * 2);
  int*    rp1  = (int*)   alloc(((size_t)N + 1) * 4);
  int*    rp2  = (int*)   alloc(((size_t)N + 1) * 4);
  uint*   E1s  = (uint*)  alloc((size_t)E1 * 4);
  uint*   E2s  = (uint*)  alloc((size_t)E2 * 4);
  int2*   S1   = (int2*)  alloc((size_t)E1 * 8);
  int2*   S2   = (int2*)  alloc((size_t)E2 * 8);
  int*    gbin1  = (int*) alloc(MAXBINS * 4);
  int*    gbin2  = (int*) alloc(MAXBINS * 4);
  int*    gbase1 = (int*) alloc(MAXBINS * 4);
  int*    gbase2 = (int*) alloc(MAXBINS * 4);
  int*    gcur1  = (int*) alloc(MAXBINS * 4);
  int*    gcur2  = (int*) alloc(MAXBINS * 4);

  hipMemsetAsync(gbin1, 0, (size_t)2 * MAXBINS * 4 + 256, stream);

  // one-time weight transpose (bf16)
  prep_weights<<<(32768 + 24576 + 255) / 256, 256, 0, stream>>>(We, Wf, Wet, Wtg);

  // embed via MFMA (no LDS; B from Wet)
  embed_mfma<<<(N + 127) / 128, 256, 0, stream>>>(x, Wet, be, hb, N);

  // binned CSR build (both graphs per launch)
  bin_hist2<<<512, 256, 0, stream>>>(a1r, E1, gbin1, a2r, E2, gbin2, nbins);
  bin_scan<<<1, 64, 0, stream>>>(gbin1, gbase1, gcur1, gbin2, gbase2, gcur2, nbins);
  bin_scatter2<<<512, 256, 0, stream>>>(
      a1r, a1c, a1v, E1, gcur1, S1, a2r, a2c, a2v, E2, gcur2, S2, nbins);
  csr_finalize<<<2 * nbins, 256, 0, stream>>>(
      S1, gbase1, rp1, E1s, E1, S2, gbase2, rp2, E2s, E2, N, nbins);

  // conv1 (gather, MLP=4, nt meta) + fused BN -> bf16 h1b
  const int NW = 2048 * 4;
  conv1_gather<<<2048, 256, 0, stream>>>(
      hb, rp1, E1s, rp2, E2s, gamma, beta, mean, var, h1b, N, NW);

  // MFMA dense tail (no LDS; B from Wtg): out base + g1b/g2b in one pass
  dense_tail_mfma<<<(N + 127) / 128, 256, 0, stream>>>(
      hb, h1b, Wtg, bf, out, g1b, g2b, N);

  // out += A1@g1 + A2@g2 (MLP=4, nt meta, bf16 gather)
  final_add_kernel<<<2048, 256, 0, stream>>>(
      g1b, g2b, rp1, E1s, rp2, E2s, out, N, NW);
}

// Round 12
// 336.192 us; speedup vs baseline: 1.0715x; 1.0715x over previous
//
#include <hip/hip_runtime.h>

#define BN_EPS 1e-5f
#define MAXBINS 128   // bins of 512 rows; requires N <= 65536 (col packs in 16 bits)

typedef __attribute__((ext_vector_type(8))) short bf16x8;
typedef __attribute__((ext_vector_type(4))) float f32x4;

__device__ __forceinline__ ushort f2bf(float f) {
  uint u = __float_as_uint(f);
  u += 0x7fffu + ((u >> 16) & 1u);
  return (ushort)(u >> 16);
}
__device__ __forceinline__ float bf2f(ushort u) {
  return __uint_as_float((uint)u << 16);
}
__device__ __forceinline__ uint pack2bf(float a, float b) {
  return (uint)f2bf(a) | ((uint)f2bf(b) << 16);
}
// acc[0..7] += v * bf16x8(wv)
__device__ __forceinline__ void fma8(float acc[8], uint4 wv, float v) {
  acc[0] += v * __uint_as_float(wv.x << 16);
  acc[1] += v * __uint_as_float(wv.x & 0xffff0000u);
  acc[2] += v * __uint_as_float(wv.y << 16);
  acc[3] += v * __uint_as_float(wv.y & 0xffff0000u);
  acc[4] += v * __uint_as_float(wv.z << 16);
  acc[5] += v * __uint_as_float(wv.z & 0xffff0000u);
  acc[6] += v * __uint_as_float(wv.w << 16);
  acc[7] += v * __uint_as_float(wv.w & 0xffff0000u);
}

// ---------------------------------------------------------------------------
// One-time weight transpose to bf16 (L2/L3-resident broadcast tables).
// ---------------------------------------------------------------------------
__global__ __launch_bounds__(256) void prep_weights(
    const float* __restrict__ We, const float* __restrict__ Wf,
    ushort* __restrict__ Wet, ushort* __restrict__ Wtg) {
  int i = blockIdx.x * 256 + threadIdx.x;
  if (i < 32768) {
    int col = i >> 9, k = i & 511;
    Wet[(size_t)col * 512 + k] = f2bf(We[(size_t)k * 64 + col]);
  } else if (i < 32768 + 24576) {
    int j = i - 32768;
    int col = j / 192, k = j % 192;
    float v = 0.f;
    if (col < 40)       v = Wf[(size_t)k * 40 + col];
    else if (col < 80)  { if (k >= 64) v = Wf[(size_t)(128 + k) * 40 + (col - 40)]; }
    else if (col < 120) { if (k >= 64) v = Wf[(size_t)(256 + k) * 40 + (col - 80)]; }
    Wtg[(size_t)col * 192 + k] = f2bf(v);
  }
}

// ---------------------------------------------------------------------------
// Embed via MFMA, no LDS: [hbA|hbB] = bf16( relu(x @ We + b) ), split [N][32].
// ---------------------------------------------------------------------------
__global__ __launch_bounds__(256) void embed_mfma(
    const float* __restrict__ x, const ushort* __restrict__ Wet,
    const float* __restrict__ b, ushort* __restrict__ hbA,
    ushort* __restrict__ hbB, int N) {
  const int tid  = threadIdx.x;
  const int wv   = tid >> 6;
  const int lane = tid & 63;
  const int m16  = lane & 15;
  const int kg   = lane >> 4;
  const int row0 = blockIdx.x * 128 + wv * 32;

  f32x4 acc[2][4];
#pragma unroll
  for (int i = 0; i < 2; ++i)
#pragma unroll
    for (int t = 0; t < 4; ++t) acc[i][t] = (f32x4){0.f, 0.f, 0.f, 0.f};

#pragma unroll 4
  for (int ks = 0; ks < 16; ++ks) {
    const int kk = ks * 32 + kg * 8;
    bf16x8 afr[2];
#pragma unroll
    for (int i = 0; i < 2; ++i) {
      int grow = row0 + i * 16 + m16;
      grow = (grow < N) ? grow : (N - 1);
      const float* ap = x + (size_t)grow * 512 + kk;
      float4 lo = *reinterpret_cast<const float4*>(ap);
      float4 hi = *reinterpret_cast<const float4*>(ap + 4);
      uint4 pk;
      pk.x = pack2bf(lo.x, lo.y); pk.y = pack2bf(lo.z, lo.w);
      pk.z = pack2bf(hi.x, hi.y); pk.w = pack2bf(hi.z, hi.w);
      afr[i] = *reinterpret_cast<const bf16x8*>(&pk);
    }
#pragma unroll
    for (int t = 0; t < 4; ++t) {
      bf16x8 bfr = *reinterpret_cast<const bf16x8*>(
          Wet + (size_t)(t * 16 + m16) * 512 + kk);
      acc[0][t] = __builtin_amdgcn_mfma_f32_16x16x32_bf16(afr[0], bfr, acc[0][t], 0, 0, 0);
      acc[1][t] = __builtin_amdgcn_mfma_f32_16x16x32_bf16(afr[1], bfr, acc[1][t], 0, 0, 0);
    }
  }

#pragma unroll
  for (int i = 0; i < 2; ++i) {
    const int rbase = row0 + i * 16 + kg * 4;
#pragma unroll
    for (int t = 0; t < 4; ++t) {
      const int col = t * 16 + m16;
      const float bias = b[col];
#pragma unroll
      for (int reg = 0; reg < 4; ++reg) {
        int gr = rbase + reg;
        if (gr < N) {
          ushort v = f2bf(fmaxf(acc[i][t][reg] + bias, 0.f));
          if (col < 32) hbA[(size_t)gr * 32 + col] = v;
          else          hbB[(size_t)gr * 32 + (col - 32)] = v;
        }
      }
    }
  }
}

// ---------------------------------------------------------------------------
// CSR build, two-level binned (bin = row>>9)  (round-9 verbatim)
// ---------------------------------------------------------------------------
__global__ __launch_bounds__(256) void bin_hist(
    const int* __restrict__ rows, int* __restrict__ gbin, int E, int nbins) {
  __shared__ int lb[MAXBINS];
  const int tid = threadIdx.x;
  if (tid < nbins) lb[tid] = 0;
  __syncthreads();
  const int stride = gridDim.x * blockDim.x;
  for (int i = blockIdx.x * blockDim.x + tid; i < E; i += stride)
    atomicAdd(&lb[rows[i] >> 9], 1);
  __syncthreads();
  if (tid < nbins && lb[tid]) atomicAdd(&gbin[tid], lb[tid]);
}

__device__ __forceinline__ void scan_bins_dev(
    const int* gbin, int* gbase, int* gcur, int nbins, int lane) {
  int carry = 0;
  for (int ch = 0; ch * 64 < nbins; ++ch) {
    int idx = ch * 64 + lane;
    int v = (idx < nbins) ? gbin[idx] : 0;
    int inc = v;
#pragma unroll
    for (int off = 1; off < 64; off <<= 1) {
      int y = __shfl_up(inc, off);
      if (lane >= off) inc += y;
    }
    int ex = carry + inc - v;
    if (idx < nbins) { gbase[idx] = ex; gcur[idx] = ex; }
    carry += __shfl(inc, 63);
  }
}

__global__ __launch_bounds__(64) void bin_scan(
    const int* __restrict__ gbin1, int* __restrict__ gbase1, int* __restrict__ gcur1,
    const int* __restrict__ gbin2, int* __restrict__ gbase2, int* __restrict__ gcur2,
    int nbins) {
  int lane = threadIdx.x;
  scan_bins_dev(gbin1, gbase1, gcur1, nbins, lane);
  scan_bins_dev(gbin2, gbase2, gcur2, nbins, lane);
}

// Staging record: int2( col | (row&511)<<16 , val_bits_f32 ).
__global__ __launch_bounds__(256) void bin_scatter(
    const int* __restrict__ rows, const int* __restrict__ cols,
    const float* __restrict__ vals, int E, int* __restrict__ gcur,
    int2* __restrict__ S, int nbins) {
  __shared__ int lcnt[MAXBINS];
  __shared__ int lcur[MAXBINS];
  const int tid = threadIdx.x;
  for (int e0 = blockIdx.x * 2048; e0 < E; e0 += gridDim.x * 2048) {
    int i0 = e0 + tid * 8;
    int r[8], c[8], vb[8];
    if (i0 + 8 <= E) {
      int4 a = *reinterpret_cast<const int4*>(rows + i0);
      int4 b = *reinterpret_cast<const int4*>(rows + i0 + 4);
      r[0]=a.x; r[1]=a.y; r[2]=a.z; r[3]=a.w; r[4]=b.x; r[5]=b.y; r[6]=b.z; r[7]=b.w;
      a = *reinterpret_cast<const int4*>(cols + i0);
      b = *reinterpret_cast<const int4*>(cols + i0 + 4);
      c[0]=a.x; c[1]=a.y; c[2]=a.z; c[3]=a.w; c[4]=b.x; c[5]=b.y; c[6]=b.z; c[7]=b.w;
      a = *reinterpret_cast<const int4*>(vals + i0);
      b = *reinterpret_cast<const int4*>(vals + i0 + 4);
      vb[0]=a.x; vb[1]=a.y; vb[2]=a.z; vb[3]=a.w; vb[4]=b.x; vb[5]=b.y; vb[6]=b.z; vb[7]=b.w;
    } else {
#pragma unroll
      for (int t = 0; t < 8; ++t) {
        int i = i0 + t;
        bool ok = i < E;
        r[t]  = ok ? rows[i] : -1;
        c[t]  = ok ? cols[i] : 0;
        vb[t] = ok ? __float_as_int(vals[i]) : 0;
      }
    }
    if (tid < nbins) lcnt[tid] = 0;
    __syncthreads();
#pragma unroll
    for (int t = 0; t < 8; ++t)
      if (r[t] >= 0) atomicAdd(&lcnt[r[t] >> 9], 1);
    __syncthreads();
    if (tid < nbins) {
      int n = lcnt[tid];
      lcur[tid] = n ? atomicAdd(&gcur[tid], n) : 0;
    }
    __syncthreads();
#pragma unroll
    for (int t = 0; t < 8; ++t) {
      if (r[t] >= 0) {
        int pos = atomicAdd(&lcur[r[t] >> 9], 1);
        S[pos] = make_int2(c[t] | ((r[t] & 511) << 16), vb[t]);
      }
    }
    __syncthreads();
  }
}

// One block per (graph, bin). Final edge record: uint( col | bf16(val)<<16 ).
__global__ __launch_bounds__(256) void csr_finalize(
    const int2* __restrict__ S1, const int* __restrict__ gbase1,
    int* __restrict__ rp1, uint* __restrict__ Eo1, int Etot1,
    const int2* __restrict__ S2, const int* __restrict__ gbase2,
    int* __restrict__ rp2, uint* __restrict__ Eo2, int Etot2,
    int N, int nbins) {
  __shared__ int cnt[512];
  __shared__ int cur[512];
  const int tid = threadIdx.x;
  const int b = blockIdx.x % nbins;
  const int g = blockIdx.x / nbins;
  const int2* S     = g ? S2 : S1;
  const int* gbase  = g ? gbase2 : gbase1;
  int* rp           = g ? rp2 : rp1;
  uint* Eo          = g ? Eo2 : Eo1;
  const int Etot    = g ? Etot2 : Etot1;

  const int base = gbase[b];
  const int end  = (b + 1 < nbins) ? gbase[b + 1] : Etot;
  const int r0   = b << 9;
  const int nrows = min(512, N - r0);

  for (int l = tid; l < 512; l += 256) cnt[l] = 0;
  __syncthreads();
  for (int j = base + tid; j < end; j += 256)
    atomicAdd(&cnt[S[j].x >> 16], 1);
  __syncthreads();
  if (tid < 64) {
    int carry = 0;
#pragma unroll
    for (int ch = 0; ch < 8; ++ch) {
      int v = cnt[ch * 64 + tid];
      int inc = v;
#pragma unroll
      for (int off = 1; off < 64; off <<= 1) {
        int y = __shfl_up(inc, off);
        if (tid >= off) inc += y;
      }
      inc += carry;
      cnt[ch * 64 + tid] = inc;
      carry = __shfl(inc, 63);
    }
  }
  __syncthreads();
  for (int l = tid; l < 512; l += 256)
    cur[l] = base + ((l > 0) ? cnt[l - 1] : 0);
  for (int l = tid; l < nrows; l += 256)
    rp[r0 + l + 1] = base + cnt[l];
  if (b == 0 && tid == 0) rp[0] = 0;
  __syncthreads();
  for (int j = base + tid; j < end; j += 256) {
    int2 m = S[j];
    int pos = atomicAdd(&cur[m.x >> 16], 1);
    Eo[pos] = (uint)(m.x & 0xffff) | ((uint)f2bf(__int_as_float(m.y)) << 16);
  }
}

// ---------------------------------------------------------------------------
// Conv1 gather half + fused BN: gathers 32 features from src ([N][32], 3.2MB,
// L2-resident), BOTH graphs, writes h1b cols [pbase,pbase+32) and
// [64+pbase, 64+pbase+32). 16 edges/VMEM (4 lanes/edge, 64B row = 1 line),
// MLP=4 via 64-edge chunks. Two sequential launches serialize working sets.
// ---------------------------------------------------------------------------
__global__ __launch_bounds__(256) void conv1_gather_half(
    const ushort* __restrict__ src,
    const int* __restrict__ rp1, const uint* __restrict__ E1,
    const int* __restrict__ rp2, const uint* __restrict__ E2,
    const float* __restrict__ gamma, const float* __restrict__ beta,
    const float* __restrict__ mean, const float* __restrict__ var,
    ushort* __restrict__ h1b, int N, int nwaves, int pbase) {
  const int wid  = (blockIdx.x * blockDim.x + threadIdx.x) >> 6;
  const int lane = threadIdx.x & 63;
  const int sub  = lane >> 2;   // 16 edge slots
  const int q    = lane & 3;    // 4 feature groups of 8

  // BN hoist for this lane's 8 output features (x2 graphs)
  float sc1[8], sh1[8], sc2[8], sh2[8];
#pragma unroll
  for (int t4 = 0; t4 < 2; ++t4) {
    int f1 = pbase + q * 8 + t4 * 4;
    float4 gm = *reinterpret_cast<const float4*>(gamma + f1);
    float4 vr = *reinterpret_cast<const float4*>(var + f1);
    float4 mn = *reinterpret_cast<const float4*>(mean + f1);
    float4 bt = *reinterpret_cast<const float4*>(beta + f1);
    float s0 = gm.x * rsqrtf(vr.x + BN_EPS), s1 = gm.y * rsqrtf(vr.y + BN_EPS);
    float s2 = gm.z * rsqrtf(vr.z + BN_EPS), s3 = gm.w * rsqrtf(vr.w + BN_EPS);
    sc1[t4 * 4 + 0] = s0; sh1[t4 * 4 + 0] = bt.x - mn.x * s0;
    sc1[t4 * 4 + 1] = s1; sh1[t4 * 4 + 1] = bt.y - mn.y * s1;
    sc1[t4 * 4 + 2] = s2; sh1[t4 * 4 + 2] = bt.z - mn.z * s2;
    sc1[t4 * 4 + 3] = s3; sh1[t4 * 4 + 3] = bt.w - mn.w * s3;
    int f2 = 64 + f1;
    gm = *reinterpret_cast<const float4*>(gamma + f2);
    vr = *reinterpret_cast<const float4*>(var + f2);
    mn = *reinterpret_cast<const float4*>(mean + f2);
    bt = *reinterpret_cast<const float4*>(beta + f2);
    s0 = gm.x * rsqrtf(vr.x + BN_EPS); s1 = gm.y * rsqrtf(vr.y + BN_EPS);
    s2 = gm.z * rsqrtf(vr.z + BN_EPS); s3 = gm.w * rsqrtf(vr.w + BN_EPS);
    sc2[t4 * 4 + 0] = s0; sh2[t4 * 4 + 0] = bt.x - mn.x * s0;
    sc2[t4 * 4 + 1] = s1; sh2[t4 * 4 + 1] = bt.y - mn.y * s1;
    sc2[t4 * 4 + 2] = s2; sh2[t4 * 4 + 2] = bt.z - mn.z * s2;
    sc2[t4 * 4 + 3] = s3; sh2[t4 * 4 + 3] = bt.w - mn.w * s3;
  }

  for (int r = wid; r < N; r += nwaves) {
    float acc1[8] = {0, 0, 0, 0, 0, 0, 0, 0};
    float acc2[8] = {0, 0, 0, 0, 0, 0, 0, 0};
    {
      int s = rp1[r], e = rp1[r + 1];
      for (int j0 = s; j0 < e; j0 += 64) {
        int j = j0 + sub;
        uint m0 = (j      < e) ? E1[j]      : 0u;
        uint m1 = (j + 16 < e) ? E1[j + 16] : 0u;
        uint m2 = (j + 32 < e) ? E1[j + 32] : 0u;
        uint m3 = (j + 48 < e) ? E1[j + 48] : 0u;
        uint4 w0 = *reinterpret_cast<const uint4*>(src + (size_t)(m0 & 0xffffu) * 32 + q * 8);
        uint4 w1 = *reinterpret_cast<const uint4*>(src + (size_t)(m1 & 0xffffu) * 32 + q * 8);
        uint4 w2 = *reinterpret_cast<const uint4*>(src + (size_t)(m2 & 0xffffu) * 32 + q * 8);
        uint4 w3 = *reinterpret_cast<const uint4*>(src + (size_t)(m3 & 0xffffu) * 32 + q * 8);
        fma8(acc1, w0, bf2f((ushort)(m0 >> 16)));
        fma8(acc1, w1, bf2f((ushort)(m1 >> 16)));
        fma8(acc1, w2, bf2f((ushort)(m2 >> 16)));
        fma8(acc1, w3, bf2f((ushort)(m3 >> 16)));
      }
    }
    {
      int s = rp2[r], e = rp2[r + 1];
      for (int j0 = s; j0 < e; j0 += 64) {
        int j = j0 + sub;
        uint m0 = (j      < e) ? E2[j]      : 0u;
        uint m1 = (j + 16 < e) ? E2[j + 16] : 0u;
        uint m2 = (j + 32 < e) ? E2[j + 32] : 0u;
        uint m3 = (j + 48 < e) ? E2[j + 48] : 0u;
        uint4 w0 = *reinterpret_cast<const uint4*>(src + (size_t)(m0 & 0xffffu) * 32 + q * 8);
        uint4 w1 = *reinterpret_cast<const uint4*>(src + (size_t)(m1 & 0xffffu) * 32 + q * 8);
        uint4 w2 = *reinterpret_cast<const uint4*>(src + (size_t)(m2 & 0xffffu) * 32 + q * 8);
        uint4 w3 = *reinterpret_cast<const uint4*>(src + (size_t)(m3 & 0xffffu) * 32 + q * 8);
        fma8(acc2, w0, bf2f((ushort)(m0 >> 16)));
        fma8(acc2, w1, bf2f((ushort)(m1 >> 16)));
        fma8(acc2, w2, bf2f((ushort)(m2 >> 16)));
        fma8(acc2, w3, bf2f((ushort)(m3 >> 16)));
      }
    }
#pragma unroll
    for (int mask = 4; mask <= 32; mask <<= 1) {
#pragma unroll
      for (int t = 0; t < 8; ++t) {
        acc1[t] += __shfl_xor(acc1[t], mask);
        acc2[t] += __shfl_xor(acc2[t], mask);
      }
    }
    if (lane < 4) {
      uint4 p1, p2;
      p1.x = pack2bf(acc1[0] * sc1[0] + sh1[0], acc1[1] * sc1[1] + sh1[1]);
      p1.y = pack2bf(acc1[2] * sc1[2] + sh1[2], acc1[3] * sc1[3] + sh1[3]);
      p1.z = pack2bf(acc1[4] * sc1[4] + sh1[4], acc1[5] * sc1[5] + sh1[5]);
      p1.w = pack2bf(acc1[6] * sc1[6] + sh1[6], acc1[7] * sc1[7] + sh1[7]);
      p2.x = pack2bf(acc2[0] * sc2[0] + sh2[0], acc2[1] * sc2[1] + sh2[1]);
      p2.y = pack2bf(acc2[2] * sc2[2] + sh2[2], acc2[3] * sc2[3] + sh2[3]);
      p2.z = pack2bf(acc2[4] * sc2[4] + sh2[4], acc2[5] * sc2[5] + sh2[5]);
      p2.w = pack2bf(acc2[6] * sc2[6] + sh2[6], acc2[7] * sc2[7] + sh2[7]);
      ushort* dst = h1b + (size_t)r * 128 + pbase + q * 8;
      *reinterpret_cast<uint4*>(dst)      = p1;
      *reinterpret_cast<uint4*>(dst + 64) = p2;
    }
  }
}

// ---------------------------------------------------------------------------
// MFMA dense tail, no LDS: A = [hbA|hbB|h1b] (N x 192 bf16), B from Wtg.
//   cols 0:40 -> out (f32,+bias); 40:80 -> g1b; 80:120 -> g2b (bf16 [N][40])
// ---------------------------------------------------------------------------
__global__ __launch_bounds__(256) void dense_tail_mfma(
    const ushort* __restrict__ hbA, const ushort* __restrict__ hbB,
    const ushort* __restrict__ h1b,
    const ushort* __restrict__ Wtg, const float* __restrict__ bfin,
    float* __restrict__ out, ushort* __restrict__ g1b, ushort* __restrict__ g2b,
    int N) {
  const int tid  = threadIdx.x;
  const int wv   = tid >> 6;
  const int lane = tid & 63;
  const int m16  = lane & 15;
  const int kg   = lane >> 4;
  const int row0 = blockIdx.x * 128;

  f32x4 acc[2][8];
#pragma unroll
  for (int i = 0; i < 2; ++i)
#pragma unroll
    for (int t = 0; t < 8; ++t) acc[i][t] = (f32x4){0.f, 0.f, 0.f, 0.f};

#pragma unroll
  for (int ks = 0; ks < 6; ++ks) {
    const int kk = ks * 32 + kg * 8;
    bf16x8 afr[2];
#pragma unroll
    for (int i = 0; i < 2; ++i) {
      int grow = row0 + wv * 32 + i * 16 + m16;
      grow = (grow < N) ? grow : (N - 1);
      const ushort* ap;
      if (ks == 0)      ap = hbA + (size_t)grow * 32 + kk;
      else if (ks == 1) ap = hbB + (size_t)grow * 32 + (kk - 32);
      else              ap = h1b + (size_t)grow * 128 + (kk - 64);
      afr[i] = *reinterpret_cast<const bf16x8*>(ap);
    }
#pragma unroll
    for (int t = 0; t < 8; ++t) {
      bf16x8 bfr = *reinterpret_cast<const bf16x8*>(
          Wtg + (size_t)(t * 16 + m16) * 192 + kk);
      acc[0][t] = __builtin_amdgcn_mfma_f32_16x16x32_bf16(afr[0], bfr, acc[0][t], 0, 0, 0);
      acc[1][t] = __builtin_amdgcn_mfma_f32_16x16x32_bf16(afr[1], bfr, acc[1][t], 0, 0, 0);
    }
  }

#pragma unroll
  for (int i = 0; i < 2; ++i) {
    const int rbase = row0 + wv * 32 + i * 16 + kg * 4;
#pragma unroll
    for (int t = 0; t < 8; ++t) {
      const int col = t * 16 + m16;
      if (col >= 120) continue;
      const float bias = (col < 40) ? bfin[col] : 0.f;
#pragma unroll
      for (int reg = 0; reg < 4; ++reg) {
        int gr = rbase + reg;
        if (gr < N) {
          float v = acc[i][t][reg];
          if (col < 40)       out[(size_t)gr * 40 + col] = v + bias;
          else if (col < 80)  g1b[(size_t)gr * 40 + (col - 40)] = f2bf(v);
          else                g2b[(size_t)gr * 40 + (col - 80)] = f2bf(v);
        }
      }
    }
  }
}

// ---------------------------------------------------------------------------
// Final add for ONE graph: out[r,:] += sum_{adj} v*g[c,:]  (g = 4MB, L2-fit
// when run alone). 32-edge chunks, MLP=4, 8-lane subgroups; lanes q<5 data.
// ---------------------------------------------------------------------------
__global__ __launch_bounds__(256) void final_add_g(
    const ushort* __restrict__ g,
    const int* __restrict__ rp, const uint* __restrict__ E,
    float* __restrict__ out, int N, int nwaves) {
  const int wid  = (blockIdx.x * blockDim.x + threadIdx.x) >> 6;
  const int lane = threadIdx.x & 63;
  const int sub  = lane >> 3;
  const int q    = lane & 7;
  const int off  = (q < 5) ? q * 8 : 0;

  for (int r = wid; r < N; r += nwaves) {
    float a[8] = {0, 0, 0, 0, 0, 0, 0, 0};
    int s = rp[r], e = rp[r + 1];
    for (int j0 = s; j0 < e; j0 += 32) {
      int j = j0 + sub;
      uint m0 = (j      < e) ? E[j]      : 0u;
      uint m1 = (j + 8  < e) ? E[j + 8]  : 0u;
      uint m2 = (j + 16 < e) ? E[j + 16] : 0u;
      uint m3 = (j + 24 < e) ? E[j + 24] : 0u;
      uint4 w0 = *reinterpret_cast<const uint4*>(g + (size_t)(m0 & 0xffffu) * 40 + off);
      uint4 w1 = *reinterpret_cast<const uint4*>(g + (size_t)(m1 & 0xffffu) * 40 + off);
      uint4 w2 = *reinterpret_cast<const uint4*>(g + (size_t)(m2 & 0xffffu) * 40 + off);
      uint4 w3 = *reinterpret_cast<const uint4*>(g + (size_t)(m3 & 0xffffu) * 40 + off);
      fma8(a, w0, bf2f((ushort)(m0 >> 16)));
      fma8(a, w1, bf2f((ushort)(m1 >> 16)));
      fma8(a, w2, bf2f((ushort)(m2 >> 16)));
      fma8(a, w3, bf2f((ushort)(m3 >> 16)));
    }
#pragma unroll
    for (int mask = 8; mask <= 32; mask <<= 1)
#pragma unroll
      for (int t = 0; t < 8; ++t) a[t] += __shfl_xor(a[t], mask);

    if (lane < 5) {
      float* p = out + (size_t)r * 40 + lane * 8;
      float4 o0 = *reinterpret_cast<const float4*>(p);
      float4 o1 = *reinterpret_cast<const float4*>(p + 4);
      o0.x += a[0]; o0.y += a[1]; o0.z += a[2]; o0.w += a[3];
      o1.x += a[4]; o1.y += a[5]; o1.z += a[6]; o1.w += a[7];
      *reinterpret_cast<float4*>(p)     = o0;
      *reinterpret_cast<float4*>(p + 4) = o1;
    }
  }
}

// ---------------------------------------------------------------------------
extern "C" void kernel_launch(void* const* d_in, const int* in_sizes, int n_in,
                              void* d_out, int out_size, void* d_ws, size_t ws_size,
                              hipStream_t stream) {
  const float* x     = (const float*)d_in[0];
  const int*   a1r   = (const int*)d_in[1];
  const int*   a1c   = (const int*)d_in[2];
  const float* a1v   = (const float*)d_in[3];
  const int*   a2r   = (const int*)d_in[4];
  const int*   a2c   = (const int*)d_in[5];
  const float* a2v   = (const float*)d_in[6];
  const float* We    = (const float*)d_in[7];
  const float* be    = (const float*)d_in[8];
  const float* gamma = (const float*)d_in[9];
  const float* beta  = (const float*)d_in[10];
  const float* mean  = (const float*)d_in[11];
  const float* var   = (const float*)d_in[12];
  const float* Wf    = (const float*)d_in[13];
  const float* bf    = (const float*)d_in[14];
  float* out = (float*)d_out;

  const int N  = in_sizes[0] / 512;
  const int E1 = in_sizes[1];
  const int E2 = in_sizes[4];
  const int nbins = (N + 511) >> 9;   // requires N <= 65536

  char* p = (char*)d_ws;
  auto alloc = [&](size_t bytes) {
    char* q = p; p += (bytes + 255) & ~(size_t)255; return q;
  };
  ushort* hbA  = (ushort*)alloc((size_t)N * 32 * 2);
  ushort* hbB  = (ushort*)alloc((size_t)N * 32 * 2);
  ushort* h1b  = (ushort*)alloc((size_t)N * 128 * 2);
  ushort* g1b  = (ushort*)alloc((size_t)N * 40 * 2);
  ushort* g2b  = (ushort*)alloc((size_t)N * 40 * 2);
  ushort* Wet  = (ushort*)alloc((size_t)64 * 512 * 2);
  ushort* Wtg  = (ushort*)alloc((size_t)128 * 192 * 2);
  int*    rp1  = (int*)   alloc(((size_t)N + 1) * 4);
  int*    rp2  = (int*)   alloc(((size_t)N + 1) * 4);
  uint*   E1s  = (uint*)  alloc((size_t)E1 * 4);
  uint*   E2s  = (uint*)  alloc((size_t)E2 * 4);
  int2*   S1   = (int2*)  alloc((size_t)E1 * 8);
  int2*   S2   = (int2*)  alloc((size_t)E2 * 8);
  int*    gbin1  = (int*) alloc(MAXBINS * 4);
  int*    gbin2  = (int*) alloc(MAXBINS * 4);
  int*    gbase1 = (int*) alloc(MAXBINS * 4);
  int*    gbase2 = (int*) alloc(MAXBINS * 4);
  int*    gcur1  = (int*) alloc(MAXBINS * 4);
  int*    gcur2  = (int*) alloc(MAXBINS * 4);

  hipMemsetAsync(gbin1, 0, (size_t)2 * MAXBINS * 4, stream);

  // one-time weight transpose (bf16)
  prep_weights<<<(32768 + 24576 + 255) / 256, 256, 0, stream>>>(We, Wf, Wet, Wtg);

  // embed via MFMA (no LDS; B from Wet), split hbA/hbB
  embed_mfma<<<(N + 127) / 128, 256, 0, stream>>>(x, Wet, be, hbA, hbB, N);

  // binned CSR build (round-9 structure)
  bin_hist<<<256, 256, 0, stream>>>(a1r, gbin1, E1, nbins);
  bin_hist<<<256, 256, 0, stream>>>(a2r, gbin2, E2, nbins);
  bin_scan<<<1, 64, 0, stream>>>(gbin1, gbase1, gcur1, gbin2, gbase2, gcur2, nbins);
  bin_scatter<<<256, 256, 0, stream>>>(a1r, a1c, a1v, E1, gcur1, S1, nbins);
  bin_scatter<<<256, 256, 0, stream>>>(a2r, a2c, a2v, E2, gcur2, S2, nbins);
  csr_finalize<<<2 * nbins, 256, 0, stream>>>(
      S1, gbase1, rp1, E1s, E1, S2, gbase2, rp2, E2s, E2, N, nbins);

  // conv1: two sequential feature-half kernels, each table L2-resident
  const int NW = 2048 * 4;
  conv1_gather_half<<<2048, 256, 0, stream>>>(
      hbA, rp1, E1s, rp2, E2s, gamma, beta, mean, var, h1b, N, NW, 0);
  conv1_gather_half<<<2048, 256, 0, stream>>>(
      hbB, rp1, E1s, rp2, E2s, gamma, beta, mean, var, h1b, N, NW, 32);

  // MFMA dense tail (no LDS): out base + g1b/g2b in one pass
  dense_tail_mfma<<<(N + 127) / 128, 256, 0, stream>>>(
      hbA, hbB, h1b, Wtg, bf, out, g1b, g2b, N);

  // final add: one kernel per graph (working set = one 4MB g table)
  final_add_g<<<2048, 256, 0, stream>>>(g1b, rp1, E1s, out, N, NW);
  final_add_g<<<2048, 256, 0, stream>>>(g2b, rp2, E2s, out, N, NW);
}

// Round 13
// 324.227 us; speedup vs baseline: 1.1111x; 1.0369x over previous
//
#include <hip/hip_runtime.h>

#define BN_EPS 1e-5f
#define MAXBINS 128   // bins of 512 rows; requires N <= 65536 (col packs in 16 bits)

typedef __attribute__((ext_vector_type(8))) short bf16x8;
typedef __attribute__((ext_vector_type(4))) float f32x4;

__device__ __forceinline__ ushort f2bf(float f) {
  uint u = __float_as_uint(f);
  u += 0x7fffu + ((u >> 16) & 1u);
  return (ushort)(u >> 16);
}
__device__ __forceinline__ float bf2f(ushort u) {
  return __uint_as_float((uint)u << 16);
}
__device__ __forceinline__ uint pack2bf(float a, float b) {
  return (uint)f2bf(a) | ((uint)f2bf(b) << 16);
}
// acc[0..7] += v * bf16x8(wv)
__device__ __forceinline__ void fma8(float acc[8], uint4 wv, float v) {
  acc[0] += v * __uint_as_float(wv.x << 16);
  acc[1] += v * __uint_as_float(wv.x & 0xffff0000u);
  acc[2] += v * __uint_as_float(wv.y << 16);
  acc[3] += v * __uint_as_float(wv.y & 0xffff0000u);
  acc[4] += v * __uint_as_float(wv.z << 16);
  acc[5] += v * __uint_as_float(wv.z & 0xffff0000u);
  acc[6] += v * __uint_as_float(wv.w << 16);
  acc[7] += v * __uint_as_float(wv.w & 0xffff0000u);
}

// ---------------------------------------------------------------------------
// One-time weight transpose to bf16 (L2/L3-resident broadcast tables).
// ---------------------------------------------------------------------------
__global__ __launch_bounds__(256) void prep_weights(
    const float* __restrict__ We, const float* __restrict__ Wf,
    ushort* __restrict__ Wet, ushort* __restrict__ Wtg) {
  int i = blockIdx.x * 256 + threadIdx.x;
  if (i < 32768) {
    int col = i >> 9, k = i & 511;
    Wet[(size_t)col * 512 + k] = f2bf(We[(size_t)k * 64 + col]);
  } else if (i < 32768 + 24576) {
    int j = i - 32768;
    int col = j / 192, k = j % 192;
    float v = 0.f;
    if (col < 40)       v = Wf[(size_t)k * 40 + col];
    else if (col < 80)  { if (k >= 64) v = Wf[(size_t)(128 + k) * 40 + (col - 40)]; }
    else if (col < 120) { if (k >= 64) v = Wf[(size_t)(256 + k) * 40 + (col - 80)]; }
    Wtg[(size_t)col * 192 + k] = f2bf(v);
  }
}

// ---------------------------------------------------------------------------
// Embed via MFMA, no LDS: hb = bf16( relu(x @ We + b) )  [N,512]@[512,64]
// ---------------------------------------------------------------------------
__global__ __launch_bounds__(256) void embed_mfma(
    const float* __restrict__ x, const ushort* __restrict__ Wet,
    const float* __restrict__ b, ushort* __restrict__ hb, int N) {
  const int tid  = threadIdx.x;
  const int wv   = tid >> 6;
  const int lane = tid & 63;
  const int m16  = lane & 15;
  const int kg   = lane >> 4;
  const int row0 = blockIdx.x * 128 + wv * 32;

  f32x4 acc[2][4];
#pragma unroll
  for (int i = 0; i < 2; ++i)
#pragma unroll
    for (int t = 0; t < 4; ++t) acc[i][t] = (f32x4){0.f, 0.f, 0.f, 0.f};

#pragma unroll 4
  for (int ks = 0; ks < 16; ++ks) {
    const int kk = ks * 32 + kg * 8;
    bf16x8 afr[2];
#pragma unroll
    for (int i = 0; i < 2; ++i) {
      int grow = row0 + i * 16 + m16;
      grow = (grow < N) ? grow : (N - 1);
      const float* ap = x + (size_t)grow * 512 + kk;
      float4 lo = *reinterpret_cast<const float4*>(ap);
      float4 hi = *reinterpret_cast<const float4*>(ap + 4);
      uint4 pk;
      pk.x = pack2bf(lo.x, lo.y); pk.y = pack2bf(lo.z, lo.w);
      pk.z = pack2bf(hi.x, hi.y); pk.w = pack2bf(hi.z, hi.w);
      afr[i] = *reinterpret_cast<const bf16x8*>(&pk);
    }
#pragma unroll
    for (int t = 0; t < 4; ++t) {
      bf16x8 bfr = *reinterpret_cast<const bf16x8*>(
          Wet + (size_t)(t * 16 + m16) * 512 + kk);
      acc[0][t] = __builtin_amdgcn_mfma_f32_16x16x32_bf16(afr[0], bfr, acc[0][t], 0, 0, 0);
      acc[1][t] = __builtin_amdgcn_mfma_f32_16x16x32_bf16(afr[1], bfr, acc[1][t], 0, 0, 0);
    }
  }

#pragma unroll
  for (int i = 0; i < 2; ++i) {
    const int rbase = row0 + i * 16 + kg * 4;
#pragma unroll
    for (int t = 0; t < 4; ++t) {
      const int col = t * 16 + m16;
      const float bias = b[col];
#pragma unroll
      for (int reg = 0; reg < 4; ++reg) {
        int gr = rbase + reg;
        if (gr < N)
          hb[(size_t)gr * 64 + col] = f2bf(fmaxf(acc[i][t][reg] + bias, 0.f));
      }
    }
  }
}

// ---------------------------------------------------------------------------
// CSR build, two-level binned (bin = row>>9)  (round-9 verbatim)
// ---------------------------------------------------------------------------
__global__ __launch_bounds__(256) void bin_hist(
    const int* __restrict__ rows, int* __restrict__ gbin, int E, int nbins) {
  __shared__ int lb[MAXBINS];
  const int tid = threadIdx.x;
  if (tid < nbins) lb[tid] = 0;
  __syncthreads();
  const int stride = gridDim.x * blockDim.x;
  for (int i = blockIdx.x * blockDim.x + tid; i < E; i += stride)
    atomicAdd(&lb[rows[i] >> 9], 1);
  __syncthreads();
  if (tid < nbins && lb[tid]) atomicAdd(&gbin[tid], lb[tid]);
}

__device__ __forceinline__ void scan_bins_dev(
    const int* gbin, int* gbase, int* gcur, int nbins, int lane) {
  int carry = 0;
  for (int ch = 0; ch * 64 < nbins; ++ch) {
    int idx = ch * 64 + lane;
    int v = (idx < nbins) ? gbin[idx] : 0;
    int inc = v;
#pragma unroll
    for (int off = 1; off < 64; off <<= 1) {
      int y = __shfl_up(inc, off);
      if (lane >= off) inc += y;
    }
    int ex = carry + inc - v;
    if (idx < nbins) { gbase[idx] = ex; gcur[idx] = ex; }
    carry += __shfl(inc, 63);
  }
}

__global__ __launch_bounds__(64) void bin_scan(
    const int* __restrict__ gbin1, int* __restrict__ gbase1, int* __restrict__ gcur1,
    const int* __restrict__ gbin2, int* __restrict__ gbase2, int* __restrict__ gcur2,
    int nbins) {
  int lane = threadIdx.x;
  scan_bins_dev(gbin1, gbase1, gcur1, nbins, lane);
  scan_bins_dev(gbin2, gbase2, gcur2, nbins, lane);
}

// Staging record: int2( col | (row&511)<<16 , val_bits_f32 ).
__global__ __launch_bounds__(256) void bin_scatter(
    const int* __restrict__ rows, const int* __restrict__ cols,
    const float* __restrict__ vals, int E, int* __restrict__ gcur,
    int2* __restrict__ S, int nbins) {
  __shared__ int lcnt[MAXBINS];
  __shared__ int lcur[MAXBINS];
  const int tid = threadIdx.x;
  for (int e0 = blockIdx.x * 2048; e0 < E; e0 += gridDim.x * 2048) {
    int i0 = e0 + tid * 8;
    int r[8], c[8], vb[8];
    if (i0 + 8 <= E) {
      int4 a = *reinterpret_cast<const int4*>(rows + i0);
      int4 b = *reinterpret_cast<const int4*>(rows + i0 + 4);
      r[0]=a.x; r[1]=a.y; r[2]=a.z; r[3]=a.w; r[4]=b.x; r[5]=b.y; r[6]=b.z; r[7]=b.w;
      a = *reinterpret_cast<const int4*>(cols + i0);
      b = *reinterpret_cast<const int4*>(cols + i0 + 4);
      c[0]=a.x; c[1]=a.y; c[2]=a.z; c[3]=a.w; c[4]=b.x; c[5]=b.y; c[6]=b.z; c[7]=b.w;
      a = *reinterpret_cast<const int4*>(vals + i0);
      b = *reinterpret_cast<const int4*>(vals + i0 + 4);
      vb[0]=a.x; vb[1]=a.y; vb[2]=a.z; vb[3]=a.w; vb[4]=b.x; vb[5]=b.y; vb[6]=b.z; vb[7]=b.w;
    } else {
#pragma unroll
      for (int t = 0; t < 8; ++t) {
        int i = i0 + t;
        bool ok = i < E;
        r[t]  = ok ? rows[i] : -1;
        c[t]  = ok ? cols[i] : 0;
        vb[t] = ok ? __float_as_int(vals[i]) : 0;
      }
    }
    if (tid < nbins) lcnt[tid] = 0;
    __syncthreads();
#pragma unroll
    for (int t = 0; t < 8; ++t)
      if (r[t] >= 0) atomicAdd(&lcnt[r[t] >> 9], 1);
    __syncthreads();
    if (tid < nbins) {
      int n = lcnt[tid];
      lcur[tid] = n ? atomicAdd(&gcur[tid], n) : 0;
    }
    __syncthreads();
#pragma unroll
    for (int t = 0; t < 8; ++t) {
      if (r[t] >= 0) {
        int pos = atomicAdd(&lcur[r[t] >> 9], 1);
        S[pos] = make_int2(c[t] | ((r[t] & 511) << 16), vb[t]);
      }
    }
    __syncthreads();
  }
}

// One block per (graph, bin). Final edge record: uint( col | bf16(val)<<16 ).
__global__ __launch_bounds__(256) void csr_finalize(
    const int2* __restrict__ S1, const int* __restrict__ gbase1,
    int* __restrict__ rp1, uint* __restrict__ Eo1, int Etot1,
    const int2* __restrict__ S2, const int* __restrict__ gbase2,
    int* __restrict__ rp2, uint* __restrict__ Eo2, int Etot2,
    int N, int nbins) {
  __shared__ int cnt[512];
  __shared__ int cur[512];
  const int tid = threadIdx.x;
  const int b = blockIdx.x % nbins;
  const int g = blockIdx.x / nbins;
  const int2* S     = g ? S2 : S1;
  const int* gbase  = g ? gbase2 : gbase1;
  int* rp           = g ? rp2 : rp1;
  uint* Eo          = g ? Eo2 : Eo1;
  const int Etot    = g ? Etot2 : Etot1;

  const int base = gbase[b];
  const int end  = (b + 1 < nbins) ? gbase[b + 1] : Etot;
  const int r0   = b << 9;
  const int nrows = min(512, N - r0);

  for (int l = tid; l < 512; l += 256) cnt[l] = 0;
  __syncthreads();
  for (int j = base + tid; j < end; j += 256)
    atomicAdd(&cnt[S[j].x >> 16], 1);
  __syncthreads();
  if (tid < 64) {
    int carry = 0;
#pragma unroll
    for (int ch = 0; ch < 8; ++ch) {
      int v = cnt[ch * 64 + tid];
      int inc = v;
#pragma unroll
      for (int off = 1; off < 64; off <<= 1) {
        int y = __shfl_up(inc, off);
        if (tid >= off) inc += y;
      }
      inc += carry;
      cnt[ch * 64 + tid] = inc;
      carry = __shfl(inc, 63);
    }
  }
  __syncthreads();
  for (int l = tid; l < 512; l += 256)
    cur[l] = base + ((l > 0) ? cnt[l - 1] : 0);
  for (int l = tid; l < nrows; l += 256)
    rp[r0 + l + 1] = base + cnt[l];
  if (b == 0 && tid == 0) rp[0] = 0;
  __syncthreads();
  for (int j = base + tid; j < end; j += 256) {
    int2 m = S[j];
    int pos = atomicAdd(&cur[m.x >> 16], 1);
    Eo[pos] = (uint)(m.x & 0xffff) | ((uint)f2bf(__int_as_float(m.y)) << 16);
  }
}

// ---------------------------------------------------------------------------
// Conv1 gather + fused BN. One wave per row (grid-stride).
// FUSED graph loops: each iteration issues 4 meta + 4 gathers for BOTH graphs
// (8 independent chains, MLP=8), rounds/row = max(chunks1, chunks2).
// ---------------------------------------------------------------------------
__global__ __launch_bounds__(256) void conv1_gather(
    const ushort* __restrict__ hb,
    const int* __restrict__ rp1, const uint* __restrict__ E1,
    const int* __restrict__ rp2, const uint* __restrict__ E2,
    const float* __restrict__ gamma, const float* __restrict__ beta,
    const float* __restrict__ mean, const float* __restrict__ var,
    ushort* __restrict__ h1b, int N, int nwaves) {
  const int wid  = (blockIdx.x * blockDim.x + threadIdx.x) >> 6;
  const int lane = threadIdx.x & 63;
  const int sub  = lane >> 3;
  const int q    = lane & 7;

  float sc1[8], sh1[8], sc2[8], sh2[8];
#pragma unroll
  for (int t4 = 0; t4 < 2; ++t4) {
    int f1 = q * 8 + t4 * 4;
    float4 gm = *reinterpret_cast<const float4*>(gamma + f1);
    float4 vr = *reinterpret_cast<const float4*>(var + f1);
    float4 mn = *reinterpret_cast<const float4*>(mean + f1);
    float4 bt = *reinterpret_cast<const float4*>(beta + f1);
    float s0 = gm.x * rsqrtf(vr.x + BN_EPS), s1 = gm.y * rsqrtf(vr.y + BN_EPS);
    float s2 = gm.z * rsqrtf(vr.z + BN_EPS), s3 = gm.w * rsqrtf(vr.w + BN_EPS);
    sc1[t4 * 4 + 0] = s0; sh1[t4 * 4 + 0] = bt.x - mn.x * s0;
    sc1[t4 * 4 + 1] = s1; sh1[t4 * 4 + 1] = bt.y - mn.y * s1;
    sc1[t4 * 4 + 2] = s2; sh1[t4 * 4 + 2] = bt.z - mn.z * s2;
    sc1[t4 * 4 + 3] = s3; sh1[t4 * 4 + 3] = bt.w - mn.w * s3;
    int f2 = 64 + f1;
    gm = *reinterpret_cast<const float4*>(gamma + f2);
    vr = *reinterpret_cast<const float4*>(var + f2);
    mn = *reinterpret_cast<const float4*>(mean + f2);
    bt = *reinterpret_cast<const float4*>(beta + f2);
    s0 = gm.x * rsqrtf(vr.x + BN_EPS); s1 = gm.y * rsqrtf(vr.y + BN_EPS);
    s2 = gm.z * rsqrtf(vr.z + BN_EPS); s3 = gm.w * rsqrtf(vr.w + BN_EPS);
    sc2[t4 * 4 + 0] = s0; sh2[t4 * 4 + 0] = bt.x - mn.x * s0;
    sc2[t4 * 4 + 1] = s1; sh2[t4 * 4 + 1] = bt.y - mn.y * s1;
    sc2[t4 * 4 + 2] = s2; sh2[t4 * 4 + 2] = bt.z - mn.z * s2;
    sc2[t4 * 4 + 3] = s3; sh2[t4 * 4 + 3] = bt.w - mn.w * s3;
  }

  for (int r = wid; r < N; r += nwaves) {
    float acc1[8] = {0, 0, 0, 0, 0, 0, 0, 0};
    float acc2[8] = {0, 0, 0, 0, 0, 0, 0, 0};
    int i1 = rp1[r], e1 = rp1[r + 1];
    int i2 = rp2[r], e2 = rp2[r + 1];
    while (i1 < e1 || i2 < e2) {
      int jA = i1 + sub, jB = i2 + sub;
      uint mA0 = (jA      < e1) ? E1[jA]      : 0u;
      uint mA1 = (jA + 8  < e1) ? E1[jA + 8]  : 0u;
      uint mA2 = (jA + 16 < e1) ? E1[jA + 16] : 0u;
      uint mA3 = (jA + 24 < e1) ? E1[jA + 24] : 0u;
      uint mB0 = (jB      < e2) ? E2[jB]      : 0u;
      uint mB1 = (jB + 8  < e2) ? E2[jB + 8]  : 0u;
      uint mB2 = (jB + 16 < e2) ? E2[jB + 16] : 0u;
      uint mB3 = (jB + 24 < e2) ? E2[jB + 24] : 0u;
      uint4 wA0 = *reinterpret_cast<const uint4*>(hb + (size_t)(mA0 & 0xffffu) * 64 + q * 8);
      uint4 wA1 = *reinterpret_cast<const uint4*>(hb + (size_t)(mA1 & 0xffffu) * 64 + q * 8);
      uint4 wA2 = *reinterpret_cast<const uint4*>(hb + (size_t)(mA2 & 0xffffu) * 64 + q * 8);
      uint4 wA3 = *reinterpret_cast<const uint4*>(hb + (size_t)(mA3 & 0xffffu) * 64 + q * 8);
      uint4 wB0 = *reinterpret_cast<const uint4*>(hb + (size_t)(mB0 & 0xffffu) * 64 + q * 8);
      uint4 wB1 = *reinterpret_cast<const uint4*>(hb + (size_t)(mB1 & 0xffffu) * 64 + q * 8);
      uint4 wB2 = *reinterpret_cast<const uint4*>(hb + (size_t)(mB2 & 0xffffu) * 64 + q * 8);
      uint4 wB3 = *reinterpret_cast<const uint4*>(hb + (size_t)(mB3 & 0xffffu) * 64 + q * 8);
      fma8(acc1, wA0, bf2f((ushort)(mA0 >> 16)));
      fma8(acc1, wA1, bf2f((ushort)(mA1 >> 16)));
      fma8(acc1, wA2, bf2f((ushort)(mA2 >> 16)));
      fma8(acc1, wA3, bf2f((ushort)(mA3 >> 16)));
      fma8(acc2, wB0, bf2f((ushort)(mB0 >> 16)));
      fma8(acc2, wB1, bf2f((ushort)(mB1 >> 16)));
      fma8(acc2, wB2, bf2f((ushort)(mB2 >> 16)));
      fma8(acc2, wB3, bf2f((ushort)(mB3 >> 16)));
      i1 += 32; i2 += 32;
    }
#pragma unroll
    for (int mask = 8; mask <= 32; mask <<= 1) {
#pragma unroll
      for (int t = 0; t < 8; ++t) {
        acc1[t] += __shfl_xor(acc1[t], mask);
        acc2[t] += __shfl_xor(acc2[t], mask);
      }
    }
    if (lane < 8) {
      uint4 p1, p2;
      p1.x = pack2bf(acc1[0] * sc1[0] + sh1[0], acc1[1] * sc1[1] + sh1[1]);
      p1.y = pack2bf(acc1[2] * sc1[2] + sh1[2], acc1[3] * sc1[3] + sh1[3]);
      p1.z = pack2bf(acc1[4] * sc1[4] + sh1[4], acc1[5] * sc1[5] + sh1[5]);
      p1.w = pack2bf(acc1[6] * sc1[6] + sh1[6], acc1[7] * sc1[7] + sh1[7]);
      p2.x = pack2bf(acc2[0] * sc2[0] + sh2[0], acc2[1] * sc2[1] + sh2[1]);
      p2.y = pack2bf(acc2[2] * sc2[2] + sh2[2], acc2[3] * sc2[3] + sh2[3]);
      p2.z = pack2bf(acc2[4] * sc2[4] + sh2[4], acc2[5] * sc2[5] + sh2[5]);
      p2.w = pack2bf(acc2[6] * sc2[6] + sh2[6], acc2[7] * sc2[7] + sh2[7]);
      ushort* dst = h1b + (size_t)r * 128 + q * 8;
      *reinterpret_cast<uint4*>(dst)      = p1;
      *reinterpret_cast<uint4*>(dst + 64) = p2;
    }
  }
}

// ---------------------------------------------------------------------------
// MFMA dense tail, no LDS: A = [hb | h1b] (N x 192 bf16), B from Wtg (L2).
//   cols 0:40 -> out (f32,+bias); 40:80 -> g1b; 80:120 -> g2b (bf16)
// ---------------------------------------------------------------------------
__global__ __launch_bounds__(256) void dense_tail_mfma(
    const ushort* __restrict__ hb, const ushort* __restrict__ h1b,
    const ushort* __restrict__ Wtg, const float* __restrict__ bfin,
    float* __restrict__ out, ushort* __restrict__ g1b, ushort* __restrict__ g2b,
    int N) {
  const int tid  = threadIdx.x;
  const int wv   = tid >> 6;
  const int lane = tid & 63;
  const int m16  = lane & 15;
  const int kg   = lane >> 4;
  const int row0 = blockIdx.x * 128;

  f32x4 acc[2][8];
#pragma unroll
  for (int i = 0; i < 2; ++i)
#pragma unroll
    for (int t = 0; t < 8; ++t) acc[i][t] = (f32x4){0.f, 0.f, 0.f, 0.f};

#pragma unroll
  for (int ks = 0; ks < 6; ++ks) {
    const int kk = ks * 32 + kg * 8;
    bf16x8 afr[2];
#pragma unroll
    for (int i = 0; i < 2; ++i) {
      int grow = row0 + wv * 32 + i * 16 + m16;
      grow = (grow < N) ? grow : (N - 1);
      const ushort* ap = (kk < 64) ? hb + (size_t)grow * 64 + kk
                                   : h1b + (size_t)grow * 128 + (kk - 64);
      afr[i] = *reinterpret_cast<const bf16x8*>(ap);
    }
#pragma unroll
    for (int t = 0; t < 8; ++t) {
      bf16x8 bfr = *reinterpret_cast<const bf16x8*>(
          Wtg + (size_t)(t * 16 + m16) * 192 + kk);
      acc[0][t] = __builtin_amdgcn_mfma_f32_16x16x32_bf16(afr[0], bfr, acc[0][t], 0, 0, 0);
      acc[1][t] = __builtin_amdgcn_mfma_f32_16x16x32_bf16(afr[1], bfr, acc[1][t], 0, 0, 0);
    }
  }

#pragma unroll
  for (int i = 0; i < 2; ++i) {
    const int rbase = row0 + wv * 32 + i * 16 + kg * 4;
#pragma unroll
    for (int t = 0; t < 8; ++t) {
      const int col = t * 16 + m16;
      if (col >= 120) continue;
      const float bias = (col < 40) ? bfin[col] : 0.f;
#pragma unroll
      for (int reg = 0; reg < 4; ++reg) {
        int gr = rbase + reg;
        if (gr < N) {
          float v = acc[i][t][reg];
          if (col < 40)       out[(size_t)gr * 40 + col] = v + bias;
          else if (col < 80)  g1b[(size_t)gr * 40 + (col - 40)] = f2bf(v);
          else                g2b[(size_t)gr * 40 + (col - 80)] = f2bf(v);
        }
      }
    }
  }
}

// ---------------------------------------------------------------------------
// Final add: out[r,:] += sum_{adj1} v*g1b[c,:] + sum_{adj2} v*g2b[c,:]
// FUSED graph loops (MLP=8), 8-lane subgroups; lanes q<5 carry real data.
// ---------------------------------------------------------------------------
__global__ __launch_bounds__(256) void final_add_kernel(
    const ushort* __restrict__ g1b, const ushort* __restrict__ g2b,
    const int* __restrict__ rp1, const uint* __restrict__ E1,
    const int* __restrict__ rp2, const uint* __restrict__ E2,
    float* __restrict__ out, int N, int nwaves) {
  const int wid  = (blockIdx.x * blockDim.x + threadIdx.x) >> 6;
  const int lane = threadIdx.x & 63;
  const int sub  = lane >> 3;
  const int q    = lane & 7;
  const int off  = (q < 5) ? q * 8 : 0;

  for (int r = wid; r < N; r += nwaves) {
    float a1[8] = {0, 0, 0, 0, 0, 0, 0, 0};
    float a2[8] = {0, 0, 0, 0, 0, 0, 0, 0};
    int i1 = rp1[r], e1 = rp1[r + 1];
    int i2 = rp2[r], e2 = rp2[r + 1];
    while (i1 < e1 || i2 < e2) {
      int jA = i1 + sub, jB = i2 + sub;
      uint mA0 = (jA      < e1) ? E1[jA]      : 0u;
      uint mA1 = (jA + 8  < e1) ? E1[jA + 8]  : 0u;
      uint mA2 = (jA + 16 < e1) ? E1[jA + 16] : 0u;
      uint mA3 = (jA + 24 < e1) ? E1[jA + 24] : 0u;
      uint mB0 = (jB      < e2) ? E2[jB]      : 0u;
      uint mB1 = (jB + 8  < e2) ? E2[jB + 8]  : 0u;
      uint mB2 = (jB + 16 < e2) ? E2[jB + 16] : 0u;
      uint mB3 = (jB + 24 < e2) ? E2[jB + 24] : 0u;
      uint4 wA0 = *reinterpret_cast<const uint4*>(g1b + (size_t)(mA0 & 0xffffu) * 40 + off);
      uint4 wA1 = *reinterpret_cast<const uint4*>(g1b + (size_t)(mA1 & 0xffffu) * 40 + off);
      uint4 wA2 = *reinterpret_cast<const uint4*>(g1b + (size_t)(mA2 & 0xffffu) * 40 + off);
      uint4 wA3 = *reinterpret_cast<const uint4*>(g1b + (size_t)(mA3 & 0xffffu) * 40 + off);
      uint4 wB0 = *reinterpret_cast<const uint4*>(g2b + (size_t)(mB0 & 0xffffu) * 40 + off);
      uint4 wB1 = *reinterpret_cast<const uint4*>(g2b + (size_t)(mB1 & 0xffffu) * 40 + off);
      uint4 wB2 = *reinterpret_cast<const uint4*>(g2b + (size_t)(mB2 & 0xffffu) * 40 + off);
      uint4 wB3 = *reinterpret_cast<const uint4*>(g2b + (size_t)(mB3 & 0xffffu) * 40 + off);
      fma8(a1, wA0, bf2f((ushort)(mA0 >> 16)));
      fma8(a1, wA1, bf2f((ushort)(mA1 >> 16)));
      fma8(a1, wA2, bf2f((ushort)(mA2 >> 16)));
      fma8(a1, wA3, bf2f((ushort)(mA3 >> 16)));
      fma8(a2, wB0, bf2f((ushort)(mB0 >> 16)));
      fma8(a2, wB1, bf2f((ushort)(mB1 >> 16)));
      fma8(a2, wB2, bf2f((ushort)(mB2 >> 16)));
      fma8(a2, wB3, bf2f((ushort)(mB3 >> 16)));
      i1 += 32; i2 += 32;
    }
#pragma unroll
    for (int mask = 8; mask <= 32; mask <<= 1) {
#pragma unroll
      for (int t = 0; t < 8; ++t) {
        a1[t] += __shfl_xor(a1[t], mask);
        a2[t] += __shfl_xor(a2[t], mask);
      }
    }
    if (lane < 5) {
      float* p = out + (size_t)r * 40 + lane * 8;
      float4 o0 = *reinterpret_cast<const float4*>(p);
      float4 o1 = *reinterpret_cast<const float4*>(p + 4);
      o0.x += a1[0] + a2[0]; o0.y += a1[1] + a2[1];
      o0.z += a1[2] + a2[2]; o0.w += a1[3] + a2[3];
      o1.x += a1[4] + a2[4]; o1.y += a1[5] + a2[5];
      o1.z += a1[6] + a2[6]; o1.w += a1[7] + a2[7];
      *reinterpret_cast<float4*>(p)     = o0;
      *reinterpret_cast<float4*>(p + 4) = o1;
    }
  }
}

// ---------------------------------------------------------------------------
extern "C" void kernel_launch(void* const* d_in, const int* in_sizes, int n_in,
                              void* d_out, int out_size, void* d_ws, size_t ws_size,
                              hipStream_t stream) {
  const float* x     = (const float*)d_in[0];
  const int*   a1r   = (const int*)d_in[1];
  const int*   a1c   = (const int*)d_in[2];
  const float* a1v   = (const float*)d_in[3];
  const int*   a2r   = (const int*)d_in[4];
  const int*   a2c   = (const int*)d_in[5];
  const float* a2v   = (const float*)d_in[6];
  const float* We    = (const float*)d_in[7];
  const float* be    = (const float*)d_in[8];
  const float* gamma = (const float*)d_in[9];
  const float* beta  = (const float*)d_in[10];
  const float* mean  = (const float*)d_in[11];
  const float* var   = (const float*)d_in[12];
  const float* Wf    = (const float*)d_in[13];
  const float* bf    = (const float*)d_in[14];
  float* out = (float*)d_out;

  const int N  = in_sizes[0] / 512;
  const int E1 = in_sizes[1];
  const int E2 = in_sizes[4];
  const int nbins = (N + 511) >> 9;   // requires N <= 65536

  char* p = (char*)d_ws;
  auto alloc = [&](size_t bytes) {
    char* q = p; p += (bytes + 255) & ~(size_t)255; return q;
  };
  ushort* hb   = (ushort*)alloc((size_t)N * 64 * 2);
  ushort* h1b  = (ushort*)alloc((size_t)N * 128 * 2);
  ushort* g1b  = (ushort*)alloc((size_t)N * 40 * 2);
  ushort* g2b  = (ushort*)alloc((size_t)N * 40 * 2);
  ushort* Wet  = (ushort*)alloc((size_t)64 * 512 * 2);
  ushort* Wtg  = (ushort*)alloc((size_t)128 * 192 * 2);
  int*    rp1  = (int*)   alloc(((size_t)N + 1) * 4);
  int*    rp2  = (int*)   alloc(((size_t)N + 1) * 4);
  uint*   E1s  = (uint*)  alloc((size_t)E1 * 4);
  uint*   E2s  = (uint*)  alloc((size_t)E2 * 4);
  int2*   S1   = (int2*)  alloc((size_t)E1 * 8);
  int2*   S2   = (int2*)  alloc((size_t)E2 * 8);
  int*    gbin1  = (int*) alloc(MAXBINS * 4);
  int*    gbin2  = (int*) alloc(MAXBINS * 4);
  int*    gbase1 = (int*) alloc(MAXBINS * 4);
  int*    gbase2 = (int*) alloc(MAXBINS * 4);
  int*    gcur1  = (int*) alloc(MAXBINS * 4);
  int*    gcur2  = (int*) alloc(MAXBINS * 4);

  hipMemsetAsync(gbin1, 0, (size_t)2 * MAXBINS * 4, stream);

  // one-time weight transpose (bf16)
  prep_weights<<<(32768 + 24576 + 255) / 256, 256, 0, stream>>>(We, Wf, Wet, Wtg);

  // embed via MFMA (no LDS; B from Wet)
  embed_mfma<<<(N + 127) / 128, 256, 0, stream>>>(x, Wet, be, hb, N);

  // binned CSR build
  bin_hist<<<256, 256, 0, stream>>>(a1r, gbin1, E1, nbins);
  bin_hist<<<256, 256, 0, stream>>>(a2r, gbin2, E2, nbins);
  bin_scan<<<1, 64, 0, stream>>>(gbin1, gbase1, gcur1, gbin2, gbase2, gcur2, nbins);
  bin_scatter<<<256, 256, 0, stream>>>(a1r, a1c, a1v, E1, gcur1, S1, nbins);
  bin_scatter<<<256, 256, 0, stream>>>(a2r, a2c, a2v, E2, gcur2, S2, nbins);
  csr_finalize<<<2 * nbins, 256, 0, stream>>>(
      S1, gbase1, rp1, E1s, E1, S2, gbase2, rp2, E2s, E2, N, nbins);

  // conv1 (fused-graph gather, MLP=8) + fused BN -> bf16 h1b
  const int NW = 2048 * 4;
  conv1_gather<<<2048, 256, 0, stream>>>(
      hb, rp1, E1s, rp2, E2s, gamma, beta, mean, var, h1b, N, NW);

  // MFMA dense tail (no LDS; B from Wtg): out base + g1b/g2b in one pass
  dense_tail_mfma<<<(N + 127) / 128, 256, 0, stream>>>(
      hb, h1b, Wtg, bf, out, g1b, g2b, N);

  // out += A1@g1 + A2@g2 (fused-graph gather, MLP=8)
  final_add_kernel<<<2048, 256, 0, stream>>>(
      g1b, g2b, rp1, E1s, rp2, E2s, out, N, NW);
}

// Round 14
// 287.284 us; speedup vs baseline: 1.2540x; 1.1286x over previous
//
#include <hip/hip_runtime.h>

#define BN_EPS 1e-5f
#define MAXBINS 128   // bins of 512 rows; requires N <= 65536 (col packs in 16 bits)

typedef __attribute__((ext_vector_type(8))) short bf16x8;
typedef __attribute__((ext_vector_type(4))) float f32x4;
typedef __attribute__((ext_vector_type(2))) float f32x2;

__device__ __forceinline__ ushort f2bf(float f) {
  uint u = __float_as_uint(f);
  u += 0x7fffu + ((u >> 16) & 1u);
  return (ushort)(u >> 16);
}
__device__ __forceinline__ float bf2f(ushort u) {
  return __uint_as_float((uint)u << 16);
}
__device__ __forceinline__ uint pack2bf(float a, float b) {
  return (uint)f2bf(a) | ((uint)f2bf(b) << 16);
}
// acc[0..3] (f32x2 pairs) += v * bf16x8(wv)  -- compiler emits v_pk_fma_f32
__device__ __forceinline__ void fma8p(f32x2 acc[4], uint4 wv, float v) {
  f32x2 vv = {v, v};
  f32x2 w;
  w.x = __uint_as_float(wv.x << 16); w.y = __uint_as_float(wv.x & 0xffff0000u);
  acc[0] += vv * w;
  w.x = __uint_as_float(wv.y << 16); w.y = __uint_as_float(wv.y & 0xffff0000u);
  acc[1] += vv * w;
  w.x = __uint_as_float(wv.z << 16); w.y = __uint_as_float(wv.z & 0xffff0000u);
  acc[2] += vv * w;
  w.x = __uint_as_float(wv.w << 16); w.y = __uint_as_float(wv.w & 0xffff0000u);
  acc[3] += vv * w;
}

// ---------------------------------------------------------------------------
// One-time weight transpose to bf16 (L2/L3-resident broadcast tables).
// ---------------------------------------------------------------------------
__global__ __launch_bounds__(256) void prep_weights(
    const float* __restrict__ We, const float* __restrict__ Wf,
    ushort* __restrict__ Wet, ushort* __restrict__ Wtg) {
  int i = blockIdx.x * 256 + threadIdx.x;
  if (i < 32768) {
    int col = i >> 9, k = i & 511;
    Wet[(size_t)col * 512 + k] = f2bf(We[(size_t)k * 64 + col]);
  } else if (i < 32768 + 24576) {
    int j = i - 32768;
    int col = j / 192, k = j % 192;
    float v = 0.f;
    if (col < 40)       v = Wf[(size_t)k * 40 + col];
    else if (col < 80)  { if (k >= 64) v = Wf[(size_t)(128 + k) * 40 + (col - 40)]; }
    else if (col < 120) { if (k >= 64) v = Wf[(size_t)(256 + k) * 40 + (col - 80)]; }
    Wtg[(size_t)col * 192 + k] = f2bf(v);
  }
}

// ---------------------------------------------------------------------------
// Embed via MFMA, no LDS: hb = bf16( relu(x @ We + b) )  [N,512]@[512,64]
// ---------------------------------------------------------------------------
__global__ __launch_bounds__(256) void embed_mfma(
    const float* __restrict__ x, const ushort* __restrict__ Wet,
    const float* __restrict__ b, ushort* __restrict__ hb, int N) {
  const int tid  = threadIdx.x;
  const int wv   = tid >> 6;
  const int lane = tid & 63;
  const int m16  = lane & 15;
  const int kg   = lane >> 4;
  const int row0 = blockIdx.x * 128 + wv * 32;

  f32x4 acc[2][4];
#pragma unroll
  for (int i = 0; i < 2; ++i)
#pragma unroll
    for (int t = 0; t < 4; ++t) acc[i][t] = (f32x4){0.f, 0.f, 0.f, 0.f};

#pragma unroll 4
  for (int ks = 0; ks < 16; ++ks) {
    const int kk = ks * 32 + kg * 8;
    bf16x8 afr[2];
#pragma unroll
    for (int i = 0; i < 2; ++i) {
      int grow = row0 + i * 16 + m16;
      grow = (grow < N) ? grow : (N - 1);
      const float* ap = x + (size_t)grow * 512 + kk;
      float4 lo = *reinterpret_cast<const float4*>(ap);
      float4 hi = *reinterpret_cast<const float4*>(ap + 4);
      uint4 pk;
      pk.x = pack2bf(lo.x, lo.y); pk.y = pack2bf(lo.z, lo.w);
      pk.z = pack2bf(hi.x, hi.y); pk.w = pack2bf(hi.z, hi.w);
      afr[i] = *reinterpret_cast<const bf16x8*>(&pk);
    }
#pragma unroll
    for (int t = 0; t < 4; ++t) {
      bf16x8 bfr = *reinterpret_cast<const bf16x8*>(
          Wet + (size_t)(t * 16 + m16) * 512 + kk);
      acc[0][t] = __builtin_amdgcn_mfma_f32_16x16x32_bf16(afr[0], bfr, acc[0][t], 0, 0, 0);
      acc[1][t] = __builtin_amdgcn_mfma_f32_16x16x32_bf16(afr[1], bfr, acc[1][t], 0, 0, 0);
    }
  }

#pragma unroll
  for (int i = 0; i < 2; ++i) {
    const int rbase = row0 + i * 16 + kg * 4;
#pragma unroll
    for (int t = 0; t < 4; ++t) {
      const int col = t * 16 + m16;
      const float bias = b[col];
#pragma unroll
      for (int reg = 0; reg < 4; ++reg) {
        int gr = rbase + reg;
        if (gr < N)
          hb[(size_t)gr * 64 + col] = f2bf(fmaxf(acc[i][t][reg] + bias, 0.f));
      }
    }
  }
}

// ---------------------------------------------------------------------------
// CSR build, two-level binned (bin = row>>9)  (round-9 verbatim)
// ---------------------------------------------------------------------------
__global__ __launch_bounds__(256) void bin_hist(
    const int* __restrict__ rows, int* __restrict__ gbin, int E, int nbins) {
  __shared__ int lb[MAXBINS];
  const int tid = threadIdx.x;
  if (tid < nbins) lb[tid] = 0;
  __syncthreads();
  const int stride = gridDim.x * blockDim.x;
  for (int i = blockIdx.x * blockDim.x + tid; i < E; i += stride)
    atomicAdd(&lb[rows[i] >> 9], 1);
  __syncthreads();
  if (tid < nbins && lb[tid]) atomicAdd(&gbin[tid], lb[tid]);
}

__device__ __forceinline__ void scan_bins_dev(
    const int* gbin, int* gbase, int* gcur, int nbins, int lane) {
  int carry = 0;
  for (int ch = 0; ch * 64 < nbins; ++ch) {
    int idx = ch * 64 + lane;
    int v = (idx < nbins) ? gbin[idx] : 0;
    int inc = v;
#pragma unroll
    for (int off = 1; off < 64; off <<= 1) {
      int y = __shfl_up(inc, off);
      if (lane >= off) inc += y;
    }
    int ex = carry + inc - v;
    if (idx < nbins) { gbase[idx] = ex; gcur[idx] = ex; }
    carry += __shfl(inc, 63);
  }
}

__global__ __launch_bounds__(64) void bin_scan(
    const int* __restrict__ gbin1, int* __restrict__ gbase1, int* __restrict__ gcur1,
    const int* __restrict__ gbin2, int* __restrict__ gbase2, int* __restrict__ gcur2,
    int nbins) {
  int lane = threadIdx.x;
  scan_bins_dev(gbin1, gbase1, gcur1, nbins, lane);
  scan_bins_dev(gbin2, gbase2, gcur2, nbins, lane);
}

// Staging record: int2( col | (row&511)<<16 , val_bits_f32 ).
__global__ __launch_bounds__(256) void bin_scatter(
    const int* __restrict__ rows, const int* __restrict__ cols,
    const float* __restrict__ vals, int E, int* __restrict__ gcur,
    int2* __restrict__ S, int nbins) {
  __shared__ int lcnt[MAXBINS];
  __shared__ int lcur[MAXBINS];
  const int tid = threadIdx.x;
  for (int e0 = blockIdx.x * 2048; e0 < E; e0 += gridDim.x * 2048) {
    int i0 = e0 + tid * 8;
    int r[8], c[8], vb[8];
    if (i0 + 8 <= E) {
      int4 a = *reinterpret_cast<const int4*>(rows + i0);
      int4 b = *reinterpret_cast<const int4*>(rows + i0 + 4);
      r[0]=a.x; r[1]=a.y; r[2]=a.z; r[3]=a.w; r[4]=b.x; r[5]=b.y; r[6]=b.z; r[7]=b.w;
      a = *reinterpret_cast<const int4*>(cols + i0);
      b = *reinterpret_cast<const int4*>(cols + i0 + 4);
      c[0]=a.x; c[1]=a.y; c[2]=a.z; c[3]=a.w; c[4]=b.x; c[5]=b.y; c[6]=b.z; c[7]=b.w;
      a = *reinterpret_cast<const int4*>(vals + i0);
      b = *reinterpret_cast<const int4*>(vals + i0 + 4);
      vb[0]=a.x; vb[1]=a.y; vb[2]=a.z; vb[3]=a.w; vb[4]=b.x; vb[5]=b.y; vb[6]=b.z; vb[7]=b.w;
    } else {
#pragma unroll
      for (int t = 0; t < 8; ++t) {
        int i = i0 + t;
        bool ok = i < E;
        r[t]  = ok ? rows[i] : -1;
        c[t]  = ok ? cols[i] : 0;
        vb[t] = ok ? __float_as_int(vals[i]) : 0;
      }
    }
    if (tid < nbins) lcnt[tid] = 0;
    __syncthreads();
#pragma unroll
    for (int t = 0; t < 8; ++t)
      if (r[t] >= 0) atomicAdd(&lcnt[r[t] >> 9], 1);
    __syncthreads();
    if (tid < nbins) {
      int n = lcnt[tid];
      lcur[tid] = n ? atomicAdd(&gcur[tid], n) : 0;
    }
    __syncthreads();
#pragma unroll
    for (int t = 0; t < 8; ++t) {
      if (r[t] >= 0) {
        int pos = atomicAdd(&lcur[r[t] >> 9], 1);
        S[pos] = make_int2(c[t] | ((r[t] & 511) << 16), vb[t]);
      }
    }
    __syncthreads();
  }
}

// One block per (graph, bin). Final edge record: uint( col | bf16(val)<<16 ).
__global__ __launch_bounds__(256) void csr_finalize(
    const int2* __restrict__ S1, const int* __restrict__ gbase1,
    int* __restrict__ rp1, uint* __restrict__ Eo1, int Etot1,
    const int2* __restrict__ S2, const int* __restrict__ gbase2,
    int* __restrict__ rp2, uint* __restrict__ Eo2, int Etot2,
    int N, int nbins) {
  __shared__ int cnt[512];
  __shared__ int cur[512];
  const int tid = threadIdx.x;
  const int b = blockIdx.x % nbins;
  const int g = blockIdx.x / nbins;
  const int2* S     = g ? S2 : S1;
  const int* gbase  = g ? gbase2 : gbase1;
  int* rp           = g ? rp2 : rp1;
  uint* Eo          = g ? Eo2 : Eo1;
  const int Etot    = g ? Etot2 : Etot1;

  const int base = gbase[b];
  const int end  = (b + 1 < nbins) ? gbase[b + 1] : Etot;
  const int r0   = b << 9;
  const int nrows = min(512, N - r0);

  for (int l = tid; l < 512; l += 256) cnt[l] = 0;
  __syncthreads();
  for (int j = base + tid; j < end; j += 256)
    atomicAdd(&cnt[S[j].x >> 16], 1);
  __syncthreads();
  if (tid < 64) {
    int carry = 0;
#pragma unroll
    for (int ch = 0; ch < 8; ++ch) {
      int v = cnt[ch * 64 + tid];
      int inc = v;
#pragma unroll
      for (int off = 1; off < 64; off <<= 1) {
        int y = __shfl_up(inc, off);
        if (tid >= off) inc += y;
      }
      inc += carry;
      cnt[ch * 64 + tid] = inc;
      carry = __shfl(inc, 63);
    }
  }
  __syncthreads();
  for (int l = tid; l < 512; l += 256)
    cur[l] = base + ((l > 0) ? cnt[l - 1] : 0);
  for (int l = tid; l < nrows; l += 256)
    rp[r0 + l + 1] = base + cnt[l];
  if (b == 0 && tid == 0) rp[0] = 0;
  __syncthreads();
  for (int j = base + tid; j < end; j += 256) {
    int2 m = S[j];
    int pos = atomicAdd(&cur[m.x >> 16], 1);
    Eo[pos] = (uint)(m.x & 0xffff) | ((uint)f2bf(__int_as_float(m.y)) << 16);
  }
}

// ---------------------------------------------------------------------------
// Conv1 gather + fused BN. One wave per row (grid-stride).
// FUSED graph loops (8 independent VMEM chains / iter), pk-math accumulate.
// ---------------------------------------------------------------------------
__global__ __launch_bounds__(256) void conv1_gather(
    const ushort* __restrict__ hb,
    const int* __restrict__ rp1, const uint* __restrict__ E1,
    const int* __restrict__ rp2, const uint* __restrict__ E2,
    const float* __restrict__ gamma, const float* __restrict__ beta,
    const float* __restrict__ mean, const float* __restrict__ var,
    ushort* __restrict__ h1b, int N, int nwaves) {
  const int wid  = (blockIdx.x * blockDim.x + threadIdx.x) >> 6;
  const int lane = threadIdx.x & 63;
  const int sub  = lane >> 3;
  const int q    = lane & 7;

  float sc1[8], sh1[8], sc2[8], sh2[8];
#pragma unroll
  for (int t4 = 0; t4 < 2; ++t4) {
    int f1 = q * 8 + t4 * 4;
    float4 gm = *reinterpret_cast<const float4*>(gamma + f1);
    float4 vr = *reinterpret_cast<const float4*>(var + f1);
    float4 mn = *reinterpret_cast<const float4*>(mean + f1);
    float4 bt = *reinterpret_cast<const float4*>(beta + f1);
    float s0 = gm.x * rsqrtf(vr.x + BN_EPS), s1 = gm.y * rsqrtf(vr.y + BN_EPS);
    float s2 = gm.z * rsqrtf(vr.z + BN_EPS), s3 = gm.w * rsqrtf(vr.w + BN_EPS);
    sc1[t4 * 4 + 0] = s0; sh1[t4 * 4 + 0] = bt.x - mn.x * s0;
    sc1[t4 * 4 + 1] = s1; sh1[t4 * 4 + 1] = bt.y - mn.y * s1;
    sc1[t4 * 4 + 2] = s2; sh1[t4 * 4 + 2] = bt.z - mn.z * s2;
    sc1[t4 * 4 + 3] = s3; sh1[t4 * 4 + 3] = bt.w - mn.w * s3;
    int f2 = 64 + f1;
    gm = *reinterpret_cast<const float4*>(gamma + f2);
    vr = *reinterpret_cast<const float4*>(var + f2);
    mn = *reinterpret_cast<const float4*>(mean + f2);
    bt = *reinterpret_cast<const float4*>(beta + f2);
    s0 = gm.x * rsqrtf(vr.x + BN_EPS); s1 = gm.y * rsqrtf(vr.y + BN_EPS);
    s2 = gm.z * rsqrtf(vr.z + BN_EPS); s3 = gm.w * rsqrtf(vr.w + BN_EPS);
    sc2[t4 * 4 + 0] = s0; sh2[t4 * 4 + 0] = bt.x - mn.x * s0;
    sc2[t4 * 4 + 1] = s1; sh2[t4 * 4 + 1] = bt.y - mn.y * s1;
    sc2[t4 * 4 + 2] = s2; sh2[t4 * 4 + 2] = bt.z - mn.z * s2;
    sc2[t4 * 4 + 3] = s3; sh2[t4 * 4 + 3] = bt.w - mn.w * s3;
  }

  for (int r = wid; r < N; r += nwaves) {
    f32x2 acc1[4] = {{0,0},{0,0},{0,0},{0,0}};
    f32x2 acc2[4] = {{0,0},{0,0},{0,0},{0,0}};
    int i1 = rp1[r], e1 = rp1[r + 1];
    int i2 = rp2[r], e2 = rp2[r + 1];
    while (i1 < e1 || i2 < e2) {
      int jA = i1 + sub, jB = i2 + sub;
      uint mA0 = (jA      < e1) ? E1[jA]      : 0u;
      uint mA1 = (jA + 8  < e1) ? E1[jA + 8]  : 0u;
      uint mA2 = (jA + 16 < e1) ? E1[jA + 16] : 0u;
      uint mA3 = (jA + 24 < e1) ? E1[jA + 24] : 0u;
      uint mB0 = (jB      < e2) ? E2[jB]      : 0u;
      uint mB1 = (jB + 8  < e2) ? E2[jB + 8]  : 0u;
      uint mB2 = (jB + 16 < e2) ? E2[jB + 16] : 0u;
      uint mB3 = (jB + 24 < e2) ? E2[jB + 24] : 0u;
      uint4 wA0 = *reinterpret_cast<const uint4*>(hb + (size_t)(mA0 & 0xffffu) * 64 + q * 8);
      uint4 wA1 = *reinterpret_cast<const uint4*>(hb + (size_t)(mA1 & 0xffffu) * 64 + q * 8);
      uint4 wA2 = *reinterpret_cast<const uint4*>(hb + (size_t)(mA2 & 0xffffu) * 64 + q * 8);
      uint4 wA3 = *reinterpret_cast<const uint4*>(hb + (size_t)(mA3 & 0xffffu) * 64 + q * 8);
      uint4 wB0 = *reinterpret_cast<const uint4*>(hb + (size_t)(mB0 & 0xffffu) * 64 + q * 8);
      uint4 wB1 = *reinterpret_cast<const uint4*>(hb + (size_t)(mB1 & 0xffffu) * 64 + q * 8);
      uint4 wB2 = *reinterpret_cast<const uint4*>(hb + (size_t)(mB2 & 0xffffu) * 64 + q * 8);
      uint4 wB3 = *reinterpret_cast<const uint4*>(hb + (size_t)(mB3 & 0xffffu) * 64 + q * 8);
      fma8p(acc1, wA0, bf2f((ushort)(mA0 >> 16)));
      fma8p(acc1, wA1, bf2f((ushort)(mA1 >> 16)));
      fma8p(acc1, wA2, bf2f((ushort)(mA2 >> 16)));
      fma8p(acc1, wA3, bf2f((ushort)(mA3 >> 16)));
      fma8p(acc2, wB0, bf2f((ushort)(mB0 >> 16)));
      fma8p(acc2, wB1, bf2f((ushort)(mB1 >> 16)));
      fma8p(acc2, wB2, bf2f((ushort)(mB2 >> 16)));
      fma8p(acc2, wB3, bf2f((ushort)(mB3 >> 16)));
      i1 += 32; i2 += 32;
    }
#pragma unroll
    for (int mask = 8; mask <= 32; mask <<= 1) {
#pragma unroll
      for (int t = 0; t < 4; ++t) {
        acc1[t].x += __shfl_xor(acc1[t].x, mask);
        acc1[t].y += __shfl_xor(acc1[t].y, mask);
        acc2[t].x += __shfl_xor(acc2[t].x, mask);
        acc2[t].y += __shfl_xor(acc2[t].y, mask);
      }
    }
    if (lane < 8) {
      uint4 p1, p2;
      p1.x = pack2bf(acc1[0].x * sc1[0] + sh1[0], acc1[0].y * sc1[1] + sh1[1]);
      p1.y = pack2bf(acc1[1].x * sc1[2] + sh1[2], acc1[1].y * sc1[3] + sh1[3]);
      p1.z = pack2bf(acc1[2].x * sc1[4] + sh1[4], acc1[2].y * sc1[5] + sh1[5]);
      p1.w = pack2bf(acc1[3].x * sc1[6] + sh1[6], acc1[3].y * sc1[7] + sh1[7]);
      p2.x = pack2bf(acc2[0].x * sc2[0] + sh2[0], acc2[0].y * sc2[1] + sh2[1]);
      p2.y = pack2bf(acc2[1].x * sc2[2] + sh2[2], acc2[1].y * sc2[3] + sh2[3]);
      p2.z = pack2bf(acc2[2].x * sc2[4] + sh2[4], acc2[2].y * sc2[5] + sh2[5]);
      p2.w = pack2bf(acc2[3].x * sc2[6] + sh2[6], acc2[3].y * sc2[7] + sh2[7]);
      ushort* dst = h1b + (size_t)r * 128 + q * 8;
      *reinterpret_cast<uint4*>(dst)      = p1;
      *reinterpret_cast<uint4*>(dst + 64) = p2;
    }
  }
}

// ---------------------------------------------------------------------------
// MFMA dense tail, no LDS: A = [hb | h1b] (N x 192 bf16), B from Wtg (L2).
//   cols 0:40 -> out (f32,+bias); 40:80 -> g1b; 80:120 -> g2b (bf16)
// ---------------------------------------------------------------------------
__global__ __launch_bounds__(256) void dense_tail_mfma(
    const ushort* __restrict__ hb, const ushort* __restrict__ h1b,
    const ushort* __restrict__ Wtg, const float* __restrict__ bfin,
    float* __restrict__ out, ushort* __restrict__ g1b, ushort* __restrict__ g2b,
    int N) {
  const int tid  = threadIdx.x;
  const int wv   = tid >> 6;
  const int lane = tid & 63;
  const int m16  = lane & 15;
  const int kg   = lane >> 4;
  const int row0 = blockIdx.x * 128;

  f32x4 acc[2][8];
#pragma unroll
  for (int i = 0; i < 2; ++i)
#pragma unroll
    for (int t = 0; t < 8; ++t) acc[i][t] = (f32x4){0.f, 0.f, 0.f, 0.f};

#pragma unroll
  for (int ks = 0; ks < 6; ++ks) {
    const int kk = ks * 32 + kg * 8;
    bf16x8 afr[2];
#pragma unroll
    for (int i = 0; i < 2; ++i) {
      int grow = row0 + wv * 32 + i * 16 + m16;
      grow = (grow < N) ? grow : (N - 1);
      const ushort* ap = (kk < 64) ? hb + (size_t)grow * 64 + kk
                                   : h1b + (size_t)grow * 128 + (kk - 64);
      afr[i] = *reinterpret_cast<const bf16x8*>(ap);
    }
#pragma unroll
    for (int t = 0; t < 8; ++t) {
      bf16x8 bfr = *reinterpret_cast<const bf16x8*>(
          Wtg + (size_t)(t * 16 + m16) * 192 + kk);
      acc[0][t] = __builtin_amdgcn_mfma_f32_16x16x32_bf16(afr[0], bfr, acc[0][t], 0, 0, 0);
      acc[1][t] = __builtin_amdgcn_mfma_f32_16x16x32_bf16(afr[1], bfr, acc[1][t], 0, 0, 0);
    }
  }

#pragma unroll
  for (int i = 0; i < 2; ++i) {
    const int rbase = row0 + wv * 32 + i * 16 + kg * 4;
#pragma unroll
    for (int t = 0; t < 8; ++t) {
      const int col = t * 16 + m16;
      if (col >= 120) continue;
      const float bias = (col < 40) ? bfin[col] : 0.f;
#pragma unroll
      for (int reg = 0; reg < 4; ++reg) {
        int gr = rbase + reg;
        if (gr < N) {
          float v = acc[i][t][reg];
          if (col < 40)       out[(size_t)gr * 40 + col] = v + bias;
          else if (col < 80)  g1b[(size_t)gr * 40 + (col - 40)] = f2bf(v);
          else                g2b[(size_t)gr * 40 + (col - 80)] = f2bf(v);
        }
      }
    }
  }
}

// ---------------------------------------------------------------------------
// Final add for ONE graph: out[r,:] += sum_{adj} v*g[c,:]  (table 4MB -> L2
// resident when run alone). 32-edge chunks, MLP=4, pk-math accumulate.
// ---------------------------------------------------------------------------
__global__ __launch_bounds__(256) void final_add_g(
    const ushort* __restrict__ g,
    const int* __restrict__ rp, const uint* __restrict__ E,
    float* __restrict__ out, int N, int nwaves) {
  const int wid  = (blockIdx.x * blockDim.x + threadIdx.x) >> 6;
  const int lane = threadIdx.x & 63;
  const int sub  = lane >> 3;
  const int q    = lane & 7;
  const int off  = (q < 5) ? q * 8 : 0;

  for (int r = wid; r < N; r += nwaves) {
    f32x2 a[4] = {{0,0},{0,0},{0,0},{0,0}};
    int s = rp[r], e = rp[r + 1];
    for (int j0 = s; j0 < e; j0 += 32) {
      int j = j0 + sub;
      uint m0 = (j      < e) ? E[j]      : 0u;
      uint m1 = (j + 8  < e) ? E[j + 8]  : 0u;
      uint m2 = (j + 16 < e) ? E[j + 16] : 0u;
      uint m3 = (j + 24 < e) ? E[j + 24] : 0u;
      uint4 w0 = *reinterpret_cast<const uint4*>(g + (size_t)(m0 & 0xffffu) * 40 + off);
      uint4 w1 = *reinterpret_cast<const uint4*>(g + (size_t)(m1 & 0xffffu) * 40 + off);
      uint4 w2 = *reinterpret_cast<const uint4*>(g + (size_t)(m2 & 0xffffu) * 40 + off);
      uint4 w3 = *reinterpret_cast<const uint4*>(g + (size_t)(m3 & 0xffffu) * 40 + off);
      fma8p(a, w0, bf2f((ushort)(m0 >> 16)));
      fma8p(a, w1, bf2f((ushort)(m1 >> 16)));
      fma8p(a, w2, bf2f((ushort)(m2 >> 16)));
      fma8p(a, w3, bf2f((ushort)(m3 >> 16)));
    }
#pragma unroll
    for (int mask = 8; mask <= 32; mask <<= 1) {
#pragma unroll
      for (int t = 0; t < 4; ++t) {
        a[t].x += __shfl_xor(a[t].x, mask);
        a[t].y += __shfl_xor(a[t].y, mask);
      }
    }
    if (lane < 5) {
      float* p = out + (size_t)r * 40 + lane * 8;
      float4 o0 = *reinterpret_cast<const float4*>(p);
      float4 o1 = *reinterpret_cast<const float4*>(p + 4);
      o0.x += a[0].x; o0.y += a[0].y; o0.z += a[1].x; o0.w += a[1].y;
      o1.x += a[2].x; o1.y += a[2].y; o1.z += a[3].x; o1.w += a[3].y;
      *reinterpret_cast<float4*>(p)     = o0;
      *reinterpret_cast<float4*>(p + 4) = o1;
    }
  }
}

// ---------------------------------------------------------------------------
extern "C" void kernel_launch(void* const* d_in, const int* in_sizes, int n_in,
                              void* d_out, int out_size, void* d_ws, size_t ws_size,
                              hipStream_t stream) {
  const float* x     = (const float*)d_in[0];
  const int*   a1r   = (const int*)d_in[1];
  const int*   a1c   = (const int*)d_in[2];
  const float* a1v   = (const float*)d_in[3];
  const int*   a2r   = (const int*)d_in[4];
  const int*   a2c   = (const int*)d_in[5];
  const float* a2v   = (const float*)d_in[6];
  const float* We    = (const float*)d_in[7];
  const float* be    = (const float*)d_in[8];
  const float* gamma = (const float*)d_in[9];
  const float* beta  = (const float*)d_in[10];
  const float* mean  = (const float*)d_in[11];
  const float* var   = (const float*)d_in[12];
  const float* Wf    = (const float*)d_in[13];
  const float* bf    = (const float*)d_in[14];
  float* out = (float*)d_out;

  const int N  = in_sizes[0] / 512;
  const int E1 = in_sizes[1];
  const int E2 = in_sizes[4];
  const int nbins = (N + 511) >> 9;   // requires N <= 65536

  char* p = (char*)d_ws;
  auto alloc = [&](size_t bytes) {
    char* q = p; p += (bytes + 255) & ~(size_t)255; return q;
  };
  ushort* hb   = (ushort*)alloc((size_t)N * 64 * 2);
  ushort* h1b  = (ushort*)alloc((size_t)N * 128 * 2);
  ushort* g1b  = (ushort*)alloc((size_t)N * 40 * 2);
  ushort* g2b  = (ushort*)alloc((size_t)N * 40 * 2);
  ushort* Wet  = (ushort*)alloc((size_t)64 * 512 * 2);
  ushort* Wtg  = (ushort*)alloc((size_t)128 * 192 * 2);
  int*    rp1  = (int*)   alloc(((size_t)N + 1) * 4);
  int*    rp2  = (int*)   alloc(((size_t)N + 1) * 4);
  uint*   E1s  = (uint*)  alloc((size_t)E1 * 4);
  uint*   E2s  = (uint*)  alloc((size_t)E2 * 4);
  int2*   S1   = (int2*)  alloc((size_t)E1 * 8);
  int2*   S2   = (int2*)  alloc((size_t)E2 * 8);
  int*    gbin1  = (int*) alloc(MAXBINS * 4);
  int*    gbin2  = (int*) alloc(MAXBINS * 4);
  int*    gbase1 = (int*) alloc(MAXBINS * 4);
  int*    gbase2 = (int*) alloc(MAXBINS * 4);
  int*    gcur1  = (int*) alloc(MAXBINS * 4);
  int*    gcur2  = (int*) alloc(MAXBINS * 4);

  hipMemsetAsync(gbin1, 0, (size_t)2 * MAXBINS * 4, stream);

  // one-time weight transpose (bf16)
  prep_weights<<<(32768 + 24576 + 255) / 256, 256, 0, stream>>>(We, Wf, Wet, Wtg);

  // embed via MFMA (no LDS; B from Wet)
  embed_mfma<<<(N + 127) / 128, 256, 0, stream>>>(x, Wet, be, hb, N);

  // binned CSR build
  bin_hist<<<256, 256, 0, stream>>>(a1r, gbin1, E1, nbins);
  bin_hist<<<256, 256, 0, stream>>>(a2r, gbin2, E2, nbins);
  bin_scan<<<1, 64, 0, stream>>>(gbin1, gbase1, gcur1, gbin2, gbase2, gcur2, nbins);
  bin_scatter<<<256, 256, 0, stream>>>(a1r, a1c, a1v, E1, gcur1, S1, nbins);
  bin_scatter<<<256, 256, 0, stream>>>(a2r, a2c, a2v, E2, gcur2, S2, nbins);
  csr_finalize<<<2 * nbins, 256, 0, stream>>>(
      S1, gbase1, rp1, E1s, E1, S2, gbase2, rp2, E2s, E2, N, nbins);

  // conv1 (fused-graph gather, MLP=8, pk-math) + fused BN -> bf16 h1b
  const int NW = 2048 * 4;
  conv1_gather<<<2048, 256, 0, stream>>>(
      hb, rp1, E1s, rp2, E2s, gamma, beta, mean, var, h1b, N, NW);

  // MFMA dense tail (no LDS; B from Wtg): out base + g1b/g2b in one pass
  dense_tail_mfma<<<(N + 127) / 128, 256, 0, stream>>>(
      hb, h1b, Wtg, bf, out, g1b, g2b, N);

  // final add: one kernel per graph (4MB table, L2-resident), pk-math
  final_add_g<<<2048, 256, 0, stream>>>(g1b, rp1, E1s, out, N, NW);
  final_add_g<<<2048, 256, 0, stream>>>(g2b, rp2, E2s, out, N, NW);
}

// Round 15
// 286.197 us; speedup vs baseline: 1.2587x; 1.0038x over previous
//
#include <hip/hip_runtime.h>

#define BN_EPS 1e-5f
#define MAXBINS 128   // bins of 512 rows; requires N <= 65536 (col packs in 16 bits)

typedef __attribute__((ext_vector_type(8))) short bf16x8;
typedef __attribute__((ext_vector_type(4))) float f32x4;
typedef __attribute__((ext_vector_type(2))) float f32x2;

__device__ __forceinline__ ushort f2bf(float f) {
  uint u = __float_as_uint(f);
  u += 0x7fffu + ((u >> 16) & 1u);
  return (ushort)(u >> 16);
}
__device__ __forceinline__ float bf2f(ushort u) {
  return __uint_as_float((uint)u << 16);
}
__device__ __forceinline__ uint pack2bf(float a, float b) {
  return (uint)f2bf(a) | ((uint)f2bf(b) << 16);
}
// acc[0..3] (f32x2 pairs) += v * bf16x8(wv)  -- compiler emits v_pk_fma_f32
__device__ __forceinline__ void fma8p(f32x2 acc[4], uint4 wv, float v) {
  f32x2 vv = {v, v};
  f32x2 w;
  w.x = __uint_as_float(wv.x << 16); w.y = __uint_as_float(wv.x & 0xffff0000u);
  acc[0] += vv * w;
  w.x = __uint_as_float(wv.y << 16); w.y = __uint_as_float(wv.y & 0xffff0000u);
  acc[1] += vv * w;
  w.x = __uint_as_float(wv.z << 16); w.y = __uint_as_float(wv.z & 0xffff0000u);
  acc[2] += vv * w;
  w.x = __uint_as_float(wv.w << 16); w.y = __uint_as_float(wv.w & 0xffff0000u);
  acc[3] += vv * w;
}

// ---------------------------------------------------------------------------
// One-time weight transpose to bf16 (L2/L3-resident broadcast tables).
// ---------------------------------------------------------------------------
__global__ __launch_bounds__(256) void prep_weights(
    const float* __restrict__ We, const float* __restrict__ Wf,
    ushort* __restrict__ Wet, ushort* __restrict__ Wtg) {
  int i = blockIdx.x * 256 + threadIdx.x;
  if (i < 32768) {
    int col = i >> 9, k = i & 511;
    Wet[(size_t)col * 512 + k] = f2bf(We[(size_t)k * 64 + col]);
  } else if (i < 32768 + 24576) {
    int j = i - 32768;
    int col = j / 192, k = j % 192;
    float v = 0.f;
    if (col < 40)       v = Wf[(size_t)k * 40 + col];
    else if (col < 80)  { if (k >= 64) v = Wf[(size_t)(128 + k) * 40 + (col - 40)]; }
    else if (col < 120) { if (k >= 64) v = Wf[(size_t)(256 + k) * 40 + (col - 80)]; }
    Wtg[(size_t)col * 192 + k] = f2bf(v);
  }
}

// ---------------------------------------------------------------------------
// Embed via MFMA, no LDS: hb = bf16( relu(x @ We + b) )  [N,512]@[512,64]
// ---------------------------------------------------------------------------
__global__ __launch_bounds__(256) void embed_mfma(
    const float* __restrict__ x, const ushort* __restrict__ Wet,
    const float* __restrict__ b, ushort* __restrict__ hb, int N) {
  const int tid  = threadIdx.x;
  const int wv   = tid >> 6;
  const int lane = tid & 63;
  const int m16  = lane & 15;
  const int kg   = lane >> 4;
  const int row0 = blockIdx.x * 128 + wv * 32;

  f32x4 acc[2][4];
#pragma unroll
  for (int i = 0; i < 2; ++i)
#pragma unroll
    for (int t = 0; t < 4; ++t) acc[i][t] = (f32x4){0.f, 0.f, 0.f, 0.f};

#pragma unroll 4
  for (int ks = 0; ks < 16; ++ks) {
    const int kk = ks * 32 + kg * 8;
    bf16x8 afr[2];
#pragma unroll
    for (int i = 0; i < 2; ++i) {
      int grow = row0 + i * 16 + m16;
      grow = (grow < N) ? grow : (N - 1);
      const float* ap = x + (size_t)grow * 512 + kk;
      float4 lo = *reinterpret_cast<const float4*>(ap);
      float4 hi = *reinterpret_cast<const float4*>(ap + 4);
      uint4 pk;
      pk.x = pack2bf(lo.x, lo.y); pk.y = pack2bf(lo.z, lo.w);
      pk.z = pack2bf(hi.x, hi.y); pk.w = pack2bf(hi.z, hi.w);
      afr[i] = *reinterpret_cast<const bf16x8*>(&pk);
    }
#pragma unroll
    for (int t = 0; t < 4; ++t) {
      bf16x8 bfr = *reinterpret_cast<const bf16x8*>(
          Wet + (size_t)(t * 16 + m16) * 512 + kk);
      acc[0][t] = __builtin_amdgcn_mfma_f32_16x16x32_bf16(afr[0], bfr, acc[0][t], 0, 0, 0);
      acc[1][t] = __builtin_amdgcn_mfma_f32_16x16x32_bf16(afr[1], bfr, acc[1][t], 0, 0, 0);
    }
  }

#pragma unroll
  for (int i = 0; i < 2; ++i) {
    const int rbase = row0 + i * 16 + kg * 4;
#pragma unroll
    for (int t = 0; t < 4; ++t) {
      const int col = t * 16 + m16;
      const float bias = b[col];
#pragma unroll
      for (int reg = 0; reg < 4; ++reg) {
        int gr = rbase + reg;
        if (gr < N)
          hb[(size_t)gr * 64 + col] = f2bf(fmaxf(acc[i][t][reg] + bias, 0.f));
      }
    }
  }
}

// ---------------------------------------------------------------------------
// CSR build, two-level binned (bin = row>>9)
// ---------------------------------------------------------------------------
__global__ __launch_bounds__(256) void bin_hist(
    const int* __restrict__ rows, int* __restrict__ gbin, int E, int nbins) {
  __shared__ int lb[MAXBINS];
  const int tid = threadIdx.x;
  if (tid < nbins) lb[tid] = 0;
  __syncthreads();
  const int stride = gridDim.x * blockDim.x;
  for (int i = blockIdx.x * blockDim.x + tid; i < E; i += stride)
    atomicAdd(&lb[rows[i] >> 9], 1);
  __syncthreads();
  if (tid < nbins && lb[tid]) atomicAdd(&gbin[tid], lb[tid]);
}

__device__ __forceinline__ void scan_bins_dev(
    const int* gbin, int* gbase, int* gcur, int nbins, int lane) {
  int carry = 0;
  for (int ch = 0; ch * 64 < nbins; ++ch) {
    int idx = ch * 64 + lane;
    int v = (idx < nbins) ? gbin[idx] : 0;
    int inc = v;
#pragma unroll
    for (int off = 1; off < 64; off <<= 1) {
      int y = __shfl_up(inc, off);
      if (lane >= off) inc += y;
    }
    int ex = carry + inc - v;
    if (idx < nbins) { gbase[idx] = ex; gcur[idx] = ex; }
    carry += __shfl(inc, 63);
  }
}

__global__ __launch_bounds__(64) void bin_scan(
    const int* __restrict__ gbin1, int* __restrict__ gbase1, int* __restrict__ gcur1,
    const int* __restrict__ gbin2, int* __restrict__ gbase2, int* __restrict__ gcur2,
    int nbins) {
  int lane = threadIdx.x;
  scan_bins_dev(gbin1, gbase1, gcur1, nbins, lane);
  scan_bins_dev(gbin2, gbase2, gcur2, nbins, lane);
}

// Staging record: int2( col | (row&511)<<16 , val_bits_f32 ).
__global__ __launch_bounds__(256) void bin_scatter(
    const int* __restrict__ rows, const int* __restrict__ cols,
    const float* __restrict__ vals, int E, int* __restrict__ gcur,
    int2* __restrict__ S, int nbins) {
  __shared__ int lcnt[MAXBINS];
  __shared__ int lcur[MAXBINS];
  const int tid = threadIdx.x;
  for (int e0 = blockIdx.x * 2048; e0 < E; e0 += gridDim.x * 2048) {
    int i0 = e0 + tid * 8;
    int r[8], c[8], vb[8];
    if (i0 + 8 <= E) {
      int4 a = *reinterpret_cast<const int4*>(rows + i0);
      int4 b = *reinterpret_cast<const int4*>(rows + i0 + 4);
      r[0]=a.x; r[1]=a.y; r[2]=a.z; r[3]=a.w; r[4]=b.x; r[5]=b.y; r[6]=b.z; r[7]=b.w;
      a = *reinterpret_cast<const int4*>(cols + i0);
      b = *reinterpret_cast<const int4*>(cols + i0 + 4);
      c[0]=a.x; c[1]=a.y; c[2]=a.z; c[3]=a.w; c[4]=b.x; c[5]=b.y; c[6]=b.z; c[7]=b.w;
      a = *reinterpret_cast<const int4*>(vals + i0);
      b = *reinterpret_cast<const int4*>(vals + i0 + 4);
      vb[0]=a.x; vb[1]=a.y; vb[2]=a.z; vb[3]=a.w; vb[4]=b.x; vb[5]=b.y; vb[6]=b.z; vb[7]=b.w;
    } else {
#pragma unroll
      for (int t = 0; t < 8; ++t) {
        int i = i0 + t;
        bool ok = i < E;
        r[t]  = ok ? rows[i] : -1;
        c[t]  = ok ? cols[i] : 0;
        vb[t] = ok ? __float_as_int(vals[i]) : 0;
      }
    }
    if (tid < nbins) lcnt[tid] = 0;
    __syncthreads();
#pragma unroll
    for (int t = 0; t < 8; ++t)
      if (r[t] >= 0) atomicAdd(&lcnt[r[t] >> 9], 1);
    __syncthreads();
    if (tid < nbins) {
      int n = lcnt[tid];
      lcur[tid] = n ? atomicAdd(&gcur[tid], n) : 0;
    }
    __syncthreads();
#pragma unroll
    for (int t = 0; t < 8; ++t) {
      if (r[t] >= 0) {
        int pos = atomicAdd(&lcur[r[t] >> 9], 1);
        S[pos] = make_int2(c[t] | ((r[t] & 511) << 16), vb[t]);
      }
    }
    __syncthreads();
  }
}

// One block per (graph, bin). Final edge record: uint( col | bf16(val)<<16 ).
__global__ __launch_bounds__(256) void csr_finalize(
    const int2* __restrict__ S1, const int* __restrict__ gbase1,
    int* __restrict__ rp1, uint* __restrict__ Eo1, int Etot1,
    const int2* __restrict__ S2, const int* __restrict__ gbase2,
    int* __restrict__ rp2, uint* __restrict__ Eo2, int Etot2,
    int N, int nbins) {
  __shared__ int cnt[512];
  __shared__ int cur[512];
  const int tid = threadIdx.x;
  const int b = blockIdx.x % nbins;
  const int g = blockIdx.x / nbins;
  const int2* S     = g ? S2 : S1;
  const int* gbase  = g ? gbase2 : gbase1;
  int* rp           = g ? rp2 : rp1;
  uint* Eo          = g ? Eo2 : Eo1;
  const int Etot    = g ? Etot2 : Etot1;

  const int base = gbase[b];
  const int end  = (b + 1 < nbins) ? gbase[b + 1] : Etot;
  const int r0   = b << 9;
  const int nrows = min(512, N - r0);

  for (int l = tid; l < 512; l += 256) cnt[l] = 0;
  __syncthreads();
  for (int j = base + tid; j < end; j += 256)
    atomicAdd(&cnt[S[j].x >> 16], 1);
  __syncthreads();
  if (tid < 64) {
    int carry = 0;
#pragma unroll
    for (int ch = 0; ch < 8; ++ch) {
      int v = cnt[ch * 64 + tid];
      int inc = v;
#pragma unroll
      for (int off = 1; off < 64; off <<= 1) {
        int y = __shfl_up(inc, off);
        if (tid >= off) inc += y;
      }
      inc += carry;
      cnt[ch * 64 + tid] = inc;
      carry = __shfl(inc, 63);
    }
  }
  __syncthreads();
  for (int l = tid; l < 512; l += 256)
    cur[l] = base + ((l > 0) ? cnt[l - 1] : 0);
  for (int l = tid; l < nrows; l += 256)
    rp[r0 + l + 1] = base + cnt[l];
  if (b == 0 && tid == 0) rp[0] = 0;
  __syncthreads();
  for (int j = base + tid; j < end; j += 256) {
    int2 m = S[j];
    int pos = atomicAdd(&cur[m.x >> 16], 1);
    Eo[pos] = (uint)(m.x & 0xffff) | ((uint)f2bf(__int_as_float(m.y)) << 16);
  }
}

// ---------------------------------------------------------------------------
// Conv1 gather + fused BN. One wave per row (grid-stride).
// Fused UNMASKED main loop (both graphs, 8 chains), then per-graph unmasked
// remainder, then one masked tail each. pk-math accumulate.
// ---------------------------------------------------------------------------
__global__ __launch_bounds__(256) void conv1_gather(
    const ushort* __restrict__ hb,
    const int* __restrict__ rp1, const uint* __restrict__ E1,
    const int* __restrict__ rp2, const uint* __restrict__ E2,
    const float* __restrict__ gamma, const float* __restrict__ beta,
    const float* __restrict__ mean, const float* __restrict__ var,
    ushort* __restrict__ h1b, int N, int nwaves) {
  const int wid  = (blockIdx.x * blockDim.x + threadIdx.x) >> 6;
  const int lane = threadIdx.x & 63;
  const int sub  = lane >> 3;
  const int q    = lane & 7;

  float sc1[8], sh1[8], sc2[8], sh2[8];
#pragma unroll
  for (int t4 = 0; t4 < 2; ++t4) {
    int f1 = q * 8 + t4 * 4;
    float4 gm = *reinterpret_cast<const float4*>(gamma + f1);
    float4 vr = *reinterpret_cast<const float4*>(var + f1);
    float4 mn = *reinterpret_cast<const float4*>(mean + f1);
    float4 bt = *reinterpret_cast<const float4*>(beta + f1);
    float s0 = gm.x * rsqrtf(vr.x + BN_EPS), s1 = gm.y * rsqrtf(vr.y + BN_EPS);
    float s2 = gm.z * rsqrtf(vr.z + BN_EPS), s3 = gm.w * rsqrtf(vr.w + BN_EPS);
    sc1[t4 * 4 + 0] = s0; sh1[t4 * 4 + 0] = bt.x - mn.x * s0;
    sc1[t4 * 4 + 1] = s1; sh1[t4 * 4 + 1] = bt.y - mn.y * s1;
    sc1[t4 * 4 + 2] = s2; sh1[t4 * 4 + 2] = bt.z - mn.z * s2;
    sc1[t4 * 4 + 3] = s3; sh1[t4 * 4 + 3] = bt.w - mn.w * s3;
    int f2 = 64 + f1;
    gm = *reinterpret_cast<const float4*>(gamma + f2);
    vr = *reinterpret_cast<const float4*>(var + f2);
    mn = *reinterpret_cast<const float4*>(mean + f2);
    bt = *reinterpret_cast<const float4*>(beta + f2);
    s0 = gm.x * rsqrtf(vr.x + BN_EPS); s1 = gm.y * rsqrtf(vr.y + BN_EPS);
    s2 = gm.z * rsqrtf(vr.z + BN_EPS); s3 = gm.w * rsqrtf(vr.w + BN_EPS);
    sc2[t4 * 4 + 0] = s0; sh2[t4 * 4 + 0] = bt.x - mn.x * s0;
    sc2[t4 * 4 + 1] = s1; sh2[t4 * 4 + 1] = bt.y - mn.y * s1;
    sc2[t4 * 4 + 2] = s2; sh2[t4 * 4 + 2] = bt.z - mn.z * s2;
    sc2[t4 * 4 + 3] = s3; sh2[t4 * 4 + 3] = bt.w - mn.w * s3;
  }

  for (int r = wid; r < N; r += nwaves) {
    f32x2 acc1[4] = {{0,0},{0,0},{0,0},{0,0}};
    f32x2 acc2[4] = {{0,0},{0,0},{0,0},{0,0}};
    int i1 = rp1[r], e1 = rp1[r + 1];
    int i2 = rp2[r], e2 = rp2[r + 1];

    // fused unmasked main loop
    while (i1 + 32 <= e1 && i2 + 32 <= e2) {
      int jA = i1 + sub, jB = i2 + sub;
      uint mA0 = E1[jA];      uint mA1 = E1[jA + 8];
      uint mA2 = E1[jA + 16]; uint mA3 = E1[jA + 24];
      uint mB0 = E2[jB];      uint mB1 = E2[jB + 8];
      uint mB2 = E2[jB + 16]; uint mB3 = E2[jB + 24];
      uint4 wA0 = *reinterpret_cast<const uint4*>(hb + (size_t)(mA0 & 0xffffu) * 64 + q * 8);
      uint4 wA1 = *reinterpret_cast<const uint4*>(hb + (size_t)(mA1 & 0xffffu) * 64 + q * 8);
      uint4 wA2 = *reinterpret_cast<const uint4*>(hb + (size_t)(mA2 & 0xffffu) * 64 + q * 8);
      uint4 wA3 = *reinterpret_cast<const uint4*>(hb + (size_t)(mA3 & 0xffffu) * 64 + q * 8);
      uint4 wB0 = *reinterpret_cast<const uint4*>(hb + (size_t)(mB0 & 0xffffu) * 64 + q * 8);
      uint4 wB1 = *reinterpret_cast<const uint4*>(hb + (size_t)(mB1 & 0xffffu) * 64 + q * 8);
      uint4 wB2 = *reinterpret_cast<const uint4*>(hb + (size_t)(mB2 & 0xffffu) * 64 + q * 8);
      uint4 wB3 = *reinterpret_cast<const uint4*>(hb + (size_t)(mB3 & 0xffffu) * 64 + q * 8);
      fma8p(acc1, wA0, bf2f((ushort)(mA0 >> 16)));
      fma8p(acc1, wA1, bf2f((ushort)(mA1 >> 16)));
      fma8p(acc1, wA2, bf2f((ushort)(mA2 >> 16)));
      fma8p(acc1, wA3, bf2f((ushort)(mA3 >> 16)));
      fma8p(acc2, wB0, bf2f((ushort)(mB0 >> 16)));
      fma8p(acc2, wB1, bf2f((ushort)(mB1 >> 16)));
      fma8p(acc2, wB2, bf2f((ushort)(mB2 >> 16)));
      fma8p(acc2, wB3, bf2f((ushort)(mB3 >> 16)));
      i1 += 32; i2 += 32;
    }
    // graph1 unmasked remainder + masked tail
    while (i1 + 32 <= e1) {
      int j = i1 + sub;
      uint m0 = E1[j];      uint m1 = E1[j + 8];
      uint m2 = E1[j + 16]; uint m3 = E1[j + 24];
      uint4 w0 = *reinterpret_cast<const uint4*>(hb + (size_t)(m0 & 0xffffu) * 64 + q * 8);
      uint4 w1 = *reinterpret_cast<const uint4*>(hb + (size_t)(m1 & 0xffffu) * 64 + q * 8);
      uint4 w2 = *reinterpret_cast<const uint4*>(hb + (size_t)(m2 & 0xffffu) * 64 + q * 8);
      uint4 w3 = *reinterpret_cast<const uint4*>(hb + (size_t)(m3 & 0xffffu) * 64 + q * 8);
      fma8p(acc1, w0, bf2f((ushort)(m0 >> 16)));
      fma8p(acc1, w1, bf2f((ushort)(m1 >> 16)));
      fma8p(acc1, w2, bf2f((ushort)(m2 >> 16)));
      fma8p(acc1, w3, bf2f((ushort)(m3 >> 16)));
      i1 += 32;
    }
    if (i1 < e1) {
      int j = i1 + sub;
      uint m0 = (j      < e1) ? E1[j]      : 0u;
      uint m1 = (j + 8  < e1) ? E1[j + 8]  : 0u;
      uint m2 = (j + 16 < e1) ? E1[j + 16] : 0u;
      uint m3 = (j + 24 < e1) ? E1[j + 24] : 0u;
      uint4 w0 = *reinterpret_cast<const uint4*>(hb + (size_t)(m0 & 0xffffu) * 64 + q * 8);
      uint4 w1 = *reinterpret_cast<const uint4*>(hb + (size_t)(m1 & 0xffffu) * 64 + q * 8);
      uint4 w2 = *reinterpret_cast<const uint4*>(hb + (size_t)(m2 & 0xffffu) * 64 + q * 8);
      uint4 w3 = *reinterpret_cast<const uint4*>(hb + (size_t)(m3 & 0xffffu) * 64 + q * 8);
      fma8p(acc1, w0, bf2f((ushort)(m0 >> 16)));
      fma8p(acc1, w1, bf2f((ushort)(m1 >> 16)));
      fma8p(acc1, w2, bf2f((ushort)(m2 >> 16)));
      fma8p(acc1, w3, bf2f((ushort)(m3 >> 16)));
    }
    // graph2 unmasked remainder + masked tail
    while (i2 + 32 <= e2) {
      int j = i2 + sub;
      uint m0 = E2[j];      uint m1 = E2[j + 8];
      uint m2 = E2[j + 16]; uint m3 = E2[j + 24];
      uint4 w0 = *reinterpret_cast<const uint4*>(hb + (size_t)(m0 & 0xffffu) * 64 + q * 8);
      uint4 w1 = *reinterpret_cast<const uint4*>(hb + (size_t)(m1 & 0xffffu) * 64 + q * 8);
      uint4 w2 = *reinterpret_cast<const uint4*>(hb + (size_t)(m2 & 0xffffu) * 64 + q * 8);
      uint4 w3 = *reinterpret_cast<const uint4*>(hb + (size_t)(m3 & 0xffffu) * 64 + q * 8);
      fma8p(acc2, w0, bf2f((ushort)(m0 >> 16)));
      fma8p(acc2, w1, bf2f((ushort)(m1 >> 16)));
      fma8p(acc2, w2, bf2f((ushort)(m2 >> 16)));
      fma8p(acc2, w3, bf2f((ushort)(m3 >> 16)));
      i2 += 32;
    }
    if (i2 < e2) {
      int j = i2 + sub;
      uint m0 = (j      < e2) ? E2[j]      : 0u;
      uint m1 = (j + 8  < e2) ? E2[j + 8]  : 0u;
      uint m2 = (j + 16 < e2) ? E2[j + 16] : 0u;
      uint m3 = (j + 24 < e2) ? E2[j + 24] : 0u;
      uint4 w0 = *reinterpret_cast<const uint4*>(hb + (size_t)(m0 & 0xffffu) * 64 + q * 8);
      uint4 w1 = *reinterpret_cast<const uint4*>(hb + (size_t)(m1 & 0xffffu) * 64 + q * 8);
      uint4 w2 = *reinterpret_cast<const uint4*>(hb + (size_t)(m2 & 0xffffu) * 64 + q * 8);
      uint4 w3 = *reinterpret_cast<const uint4*>(hb + (size_t)(m3 & 0xffffu) * 64 + q * 8);
      fma8p(acc2, w0, bf2f((ushort)(m0 >> 16)));
      fma8p(acc2, w1, bf2f((ushort)(m1 >> 16)));
      fma8p(acc2, w2, bf2f((ushort)(m2 >> 16)));
      fma8p(acc2, w3, bf2f((ushort)(m3 >> 16)));
    }

#pragma unroll
    for (int mask = 8; mask <= 32; mask <<= 1) {
#pragma unroll
      for (int t = 0; t < 4; ++t) {
        acc1[t].x += __shfl_xor(acc1[t].x, mask);
        acc1[t].y += __shfl_xor(acc1[t].y, mask);
        acc2[t].x += __shfl_xor(acc2[t].x, mask);
        acc2[t].y += __shfl_xor(acc2[t].y, mask);
      }
    }
    if (lane < 8) {
      uint4 p1, p2;
      p1.x = pack2bf(acc1[0].x * sc1[0] + sh1[0], acc1[0].y * sc1[1] + sh1[1]);
      p1.y = pack2bf(acc1[1].x * sc1[2] + sh1[2], acc1[1].y * sc1[3] + sh1[3]);
      p1.z = pack2bf(acc1[2].x * sc1[4] + sh1[4], acc1[2].y * sc1[5] + sh1[5]);
      p1.w = pack2bf(acc1[3].x * sc1[6] + sh1[6], acc1[3].y * sc1[7] + sh1[7]);
      p2.x = pack2bf(acc2[0].x * sc2[0] + sh2[0], acc2[0].y * sc2[1] + sh2[1]);
      p2.y = pack2bf(acc2[1].x * sc2[2] + sh2[2], acc2[1].y * sc2[3] + sh2[3]);
      p2.z = pack2bf(acc2[2].x * sc2[4] + sh2[4], acc2[2].y * sc2[5] + sh2[5]);
      p2.w = pack2bf(acc2[3].x * sc2[6] + sh2[6], acc2[3].y * sc2[7] + sh2[7]);
      ushort* dst = h1b + (size_t)r * 128 + q * 8;
      *reinterpret_cast<uint4*>(dst)      = p1;
      *reinterpret_cast<uint4*>(dst + 64) = p2;
    }
  }
}

// ---------------------------------------------------------------------------
// MFMA dense tail, no LDS: A = [hb | h1b] (N x 192 bf16), B from Wtg (L2).
//   cols 0:40 -> out (f32,+bias); 40:80 -> g1b; 80:120 -> g2b (bf16)
// ---------------------------------------------------------------------------
__global__ __launch_bounds__(256) void dense_tail_mfma(
    const ushort* __restrict__ hb, const ushort* __restrict__ h1b,
    const ushort* __restrict__ Wtg, const float* __restrict__ bfin,
    float* __restrict__ out, ushort* __restrict__ g1b, ushort* __restrict__ g2b,
    int N) {
  const int tid  = threadIdx.x;
  const int wv   = tid >> 6;
  const int lane = tid & 63;
  const int m16  = lane & 15;
  const int kg   = lane >> 4;
  const int row0 = blockIdx.x * 128;

  f32x4 acc[2][8];
#pragma unroll
  for (int i = 0; i < 2; ++i)
#pragma unroll
    for (int t = 0; t < 8; ++t) acc[i][t] = (f32x4){0.f, 0.f, 0.f, 0.f};

#pragma unroll
  for (int ks = 0; ks < 6; ++ks) {
    const int kk = ks * 32 + kg * 8;
    bf16x8 afr[2];
#pragma unroll
    for (int i = 0; i < 2; ++i) {
      int grow = row0 + wv * 32 + i * 16 + m16;
      grow = (grow < N) ? grow : (N - 1);
      const ushort* ap = (kk < 64) ? hb + (size_t)grow * 64 + kk
                                   : h1b + (size_t)grow * 128 + (kk - 64);
      afr[i] = *reinterpret_cast<const bf16x8*>(ap);
    }
#pragma unroll
    for (int t = 0; t < 8; ++t) {
      bf16x8 bfr = *reinterpret_cast<const bf16x8*>(
          Wtg + (size_t)(t * 16 + m16) * 192 + kk);
      acc[0][t] = __builtin_amdgcn_mfma_f32_16x16x32_bf16(afr[0], bfr, acc[0][t], 0, 0, 0);
      acc[1][t] = __builtin_amdgcn_mfma_f32_16x16x32_bf16(afr[1], bfr, acc[1][t], 0, 0, 0);
    }
  }

#pragma unroll
  for (int i = 0; i < 2; ++i) {
    const int rbase = row0 + wv * 32 + i * 16 + kg * 4;
#pragma unroll
    for (int t = 0; t < 8; ++t) {
      const int col = t * 16 + m16;
      if (col >= 120) continue;
      const float bias = (col < 40) ? bfin[col] : 0.f;
#pragma unroll
      for (int reg = 0; reg < 4; ++reg) {
        int gr = rbase + reg;
        if (gr < N) {
          float v = acc[i][t][reg];
          if (col < 40)       out[(size_t)gr * 40 + col] = v + bias;
          else if (col < 80)  g1b[(size_t)gr * 40 + (col - 40)] = f2bf(v);
          else                g2b[(size_t)gr * 40 + (col - 80)] = f2bf(v);
        }
      }
    }
  }
}

// ---------------------------------------------------------------------------
// Final add for ONE graph: out[r,:] += sum_{adj} v*g[c,:]  (table 4MB -> L2
// resident when run alone). Unmasked main loop + masked tail, pk-math.
// ---------------------------------------------------------------------------
__global__ __launch_bounds__(256) void final_add_g(
    const ushort* __restrict__ g,
    const int* __restrict__ rp, const uint* __restrict__ E,
    float* __restrict__ out, int N, int nwaves) {
  const int wid  = (blockIdx.x * blockDim.x + threadIdx.x) >> 6;
  const int lane = threadIdx.x & 63;
  const int sub  = lane >> 3;
  const int q    = lane & 7;
  const int off  = (q < 5) ? q * 8 : 0;

  for (int r = wid; r < N; r += nwaves) {
    f32x2 a[4] = {{0,0},{0,0},{0,0},{0,0}};
    int j0 = rp[r], e = rp[r + 1];
    while (j0 + 32 <= e) {
      int j = j0 + sub;
      uint m0 = E[j];      uint m1 = E[j + 8];
      uint m2 = E[j + 16]; uint m3 = E[j + 24];
      uint4 w0 = *reinterpret_cast<const uint4*>(g + (size_t)(m0 & 0xffffu) * 40 + off);
      uint4 w1 = *reinterpret_cast<const uint4*>(g + (size_t)(m1 & 0xffffu) * 40 + off);
      uint4 w2 = *reinterpret_cast<const uint4*>(g + (size_t)(m2 & 0xffffu) * 40 + off);
      uint4 w3 = *reinterpret_cast<const uint4*>(g + (size_t)(m3 & 0xffffu) * 40 + off);
      fma8p(a, w0, bf2f((ushort)(m0 >> 16)));
      fma8p(a, w1, bf2f((ushort)(m1 >> 16)));
      fma8p(a, w2, bf2f((ushort)(m2 >> 16)));
      fma8p(a, w3, bf2f((ushort)(m3 >> 16)));
      j0 += 32;
    }
    if (j0 < e) {
      int j = j0 + sub;
      uint m0 = (j      < e) ? E[j]      : 0u;
      uint m1 = (j + 8  < e) ? E[j + 8]  : 0u;
      uint m2 = (j + 16 < e) ? E[j + 16] : 0u;
      uint m3 = (j + 24 < e) ? E[j + 24] : 0u;
      uint4 w0 = *reinterpret_cast<const uint4*>(g + (size_t)(m0 & 0xffffu) * 40 + off);
      uint4 w1 = *reinterpret_cast<const uint4*>(g + (size_t)(m1 & 0xffffu) * 40 + off);
      uint4 w2 = *reinterpret_cast<const uint4*>(g + (size_t)(m2 & 0xffffu) * 40 + off);
      uint4 w3 = *reinterpret_cast<const uint4*>(g + (size_t)(m3 & 0xffffu) * 40 + off);
      fma8p(a, w0, bf2f((ushort)(m0 >> 16)));
      fma8p(a, w1, bf2f((ushort)(m1 >> 16)));
      fma8p(a, w2, bf2f((ushort)(m2 >> 16)));
      fma8p(a, w3, bf2f((ushort)(m3 >> 16)));
    }
#pragma unroll
    for (int mask = 8; mask <= 32; mask <<= 1) {
#pragma unroll
      for (int t = 0; t < 4; ++t) {
        a[t].x += __shfl_xor(a[t].x, mask);
        a[t].y += __shfl_xor(a[t].y, mask);
      }
    }
    if (lane < 5) {
      float* p = out + (size_t)r * 40 + lane * 8;
      float4 o0 = *reinterpret_cast<const float4*>(p);
      float4 o1 = *reinterpret_cast<const float4*>(p + 4);
      o0.x += a[0].x; o0.y += a[0].y; o0.z += a[1].x; o0.w += a[1].y;
      o1.x += a[2].x; o1.y += a[2].y; o1.z += a[3].x; o1.w += a[3].y;
      *reinterpret_cast<float4*>(p)     = o0;
      *reinterpret_cast<float4*>(p + 4) = o1;
    }
  }
}

// ---------------------------------------------------------------------------
extern "C" void kernel_launch(void* const* d_in, const int* in_sizes, int n_in,
                              void* d_out, int out_size, void* d_ws, size_t ws_size,
                              hipStream_t stream) {
  const float* x     = (const float*)d_in[0];
  const int*   a1r   = (const int*)d_in[1];
  const int*   a1c   = (const int*)d_in[2];
  const float* a1v   = (const float*)d_in[3];
  const int*   a2r   = (const int*)d_in[4];
  const int*   a2c   = (const int*)d_in[5];
  const float* a2v   = (const float*)d_in[6];
  const float* We    = (const float*)d_in[7];
  const float* be    = (const float*)d_in[8];
  const float* gamma = (const float*)d_in[9];
  const float* beta  = (const float*)d_in[10];
  const float* mean  = (const float*)d_in[11];
  const float* var   = (const float*)d_in[12];
  const float* Wf    = (const float*)d_in[13];
  const float* bf    = (const float*)d_in[14];
  float* out = (float*)d_out;

  const int N  = in_sizes[0] / 512;
  const int E1 = in_sizes[1];
  const int E2 = in_sizes[4];
  const int nbins = (N + 511) >> 9;   // requires N <= 65536

  char* p = (char*)d_ws;
  auto alloc = [&](size_t bytes) {
    char* q = p; p += (bytes + 255) & ~(size_t)255; return q;
  };
  ushort* hb   = (ushort*)alloc((size_t)N * 64 * 2);
  ushort* h1b  = (ushort*)alloc((size_t)N * 128 * 2);
  ushort* g1b  = (ushort*)alloc((size_t)N * 40 * 2);
  ushort* g2b  = (ushort*)alloc((size_t)N * 40 * 2);
  ushort* Wet  = (ushort*)alloc((size_t)64 * 512 * 2);
  ushort* Wtg  = (ushort*)alloc((size_t)128 * 192 * 2);
  int*    rp1  = (int*)   alloc(((size_t)N + 1) * 4);
  int*    rp2  = (int*)   alloc(((size_t)N + 1) * 4);
  uint*   E1s  = (uint*)  alloc((size_t)E1 * 4);
  uint*   E2s  = (uint*)  alloc((size_t)E2 * 4);
  int2*   S1   = (int2*)  alloc((size_t)E1 * 8);
  int2*   S2   = (int2*)  alloc((size_t)E2 * 8);
  int*    gbin1  = (int*) alloc(MAXBINS * 4);
  int*    gbin2  = (int*) alloc(MAXBINS * 4);
  int*    gbase1 = (int*) alloc(MAXBINS * 4);
  int*    gbase2 = (int*) alloc(MAXBINS * 4);
  int*    gcur1  = (int*) alloc(MAXBINS * 4);
  int*    gcur2  = (int*) alloc(MAXBINS * 4);

  hipMemsetAsync(gbin1, 0, (size_t)2 * MAXBINS * 4, stream);

  // one-time weight transpose (bf16)
  prep_weights<<<(32768 + 24576 + 255) / 256, 256, 0, stream>>>(We, Wf, Wet, Wtg);

  // embed via MFMA (no LDS; B from Wet)
  embed_mfma<<<(N + 127) / 128, 256, 0, stream>>>(x, Wet, be, hb, N);

  // binned CSR build
  bin_hist<<<256, 256, 0, stream>>>(a1r, gbin1, E1, nbins);
  bin_hist<<<256, 256, 0, stream>>>(a2r, gbin2, E2, nbins);
  bin_scan<<<1, 64, 0, stream>>>(gbin1, gbase1, gcur1, gbin2, gbase2, gcur2, nbins);
  bin_scatter<<<256, 256, 0, stream>>>(a1r, a1c, a1v, E1, gcur1, S1, nbins);
  bin_scatter<<<256, 256, 0, stream>>>(a2r, a2c, a2v, E2, gcur2, S2, nbins);
  csr_finalize<<<2 * nbins, 256, 0, stream>>>(
      S1, gbase1, rp1, E1s, E1, S2, gbase2, rp2, E2s, E2, N, nbins);

  // conv1 (fused gather, unmasked main loop, pk-math) + BN -> bf16 h1b
  const int NW = 2048 * 4;
  conv1_gather<<<2048, 256, 0, stream>>>(
      hb, rp1, E1s, rp2, E2s, gamma, beta, mean, var, h1b, N, NW);

  // MFMA dense tail (no LDS; B from Wtg): out base + g1b/g2b in one pass
  dense_tail_mfma<<<(N + 127) / 128, 256, 0, stream>>>(
      hb, h1b, Wtg, bf, out, g1b, g2b, N);

  // final add: one kernel per graph (4MB table, L2-resident), pk-math
  final_add_g<<<2048, 256, 0, stream>>>(g1b, rp1, E1s, out, N, NW);
  final_add_g<<<2048, 256, 0, stream>>>(g2b, rp2, E2s, out, N, NW);
}